// Round 13
// baseline (258.714 us; speedup 1.0000x reference)
//
#include <hip/hip_runtime.h>
#include <math.h>

#define BB_ 2
#define HH 48
#define WW 48
#define LL 2304
#define CIN 96
#define DD 192
#define KK 4
#define NN 16
#define RR 6
#define NCH 96
#define LC 24
#define COUT 192
#define OH 24
#define OW 24
#define OHW 576
#define NPX 1152
#define NTOT 4608
#define EPSF 1e-5f

typedef __attribute__((ext_vector_type(8))) short bf16x8;
typedef __attribute__((ext_vector_type(4))) float f32x4;

__device__ __forceinline__ short f2bf(float f) {
  unsigned u = __float_as_uint(f);
  unsigned r = (u + 0x7fffu + ((u >> 16) & 1u)) >> 16;
  return (short)r;
}

// ---------------- K1: prep: LN stats, WgTb, bf16 weights, xb transpose -------
__global__ __launch_bounds__(256) void k_prep(const float* __restrict__ x,
                                              const float* __restrict__ g,
                                              const float* __restrict__ b,
                                              const float* __restrict__ inw,
                                              const float* __restrict__ xpw,
                                              const float* __restrict__ w31,
                                              const float* __restrict__ w32,
                                              const float* __restrict__ w33,
                                              const float* __restrict__ w1,
                                              const float* __restrict__ wout,
                                              float* __restrict__ stats,
                                              short* __restrict__ WgTb,
                                              float* __restrict__ sWg,
                                              float* __restrict__ sWb,
                                              short* __restrict__ At3p,
                                              short* __restrict__ At1b,
                                              short* __restrict__ At2b,
                                              short* __restrict__ woutb,
                                              short* __restrict__ xb) {
  __shared__ float tile[32][33];
  int bx = blockIdx.x;
  int tid = threadIdx.x;
  if (bx < 72) {
    int bb = bx / 36; int l0 = (bx % 36) * 64;
    int p = tid >> 2, q = tid & 3;
    int l = l0 + p;
    const float* xp = x + bb * CIN * LL + l;
    float s = 0.f, ss = 0.f;
    for (int c = q; c < CIN; c += 4) { float v = xp[c * LL]; s += v; ss += v * v; }
    s += __shfl_xor(s, 1, 64); s += __shfl_xor(s, 2, 64);
    ss += __shfl_xor(ss, 1, 64); ss += __shfl_xor(ss, 2, 64);
    if (q == 0) {
      float m = s / CIN; float var = ss / CIN - m * m;
      stats[(bb * LL + l) * 2 + 0] = m;
      stats[(bb * LL + l) * 2 + 1] = rsqrtf(var + EPSF);
    }
  } else if (bx == 72) {
    for (int e = tid; e < 2 * DD; e += 256) {
      float swg = 0.f, swb = 0.f;
      for (int c = 0; c < CIN; c++) {
        float w = inw[e * CIN + c];
        float wg = w * g[c];
        WgTb[e * CIN + c] = f2bf(wg);
        swg += wg; swb += w * b[c];
      }
      sWg[e] = swg; sWb[e] = swb;
    }
  } else if (bx < 217) {
    int idx = (bx - 73) * 256 + tid;
    if (idx < 4 * 48 * 192) {
      int m = idx / 192, d = idx - m * 192;
      int kd = m / 48, r = m - kd * 48;
      At3p[idx] = (r < 38) ? f2bf(xpw[(kd * 38 + r) * 192 + d]) : (short)0;
    }
  } else if (bx < 2161) {
    int i = (bx - 217) * 256 + tid;
    if (i < 497664) {
      float v;
      if (i < 165888) v = w31[i];
      else if (i < 331776) v = w32[i - 165888];
      else {
        int k = i % 864; int m = i / 864 - 384;
        v = (k % 9 == 4) ? w1[m * 96 + k / 9] : 0.f;
      }
      At1b[i] = f2bf(v);
    }
  } else if (bx < 3457) {
    int i = (bx - 2161) * 256 + tid;
    if (i < 331776) At2b[i] = f2bf(w33[i]);
  } else if (bx < 3529) {
    int i = (bx - 3457) * 256 + tid;
    if (i < 18432) woutb[i] = f2bf(wout[i]);
  } else {
    int tt = bx - 3529;
    int bb = tt / 216; int r2 = tt % 216;
    int ct = r2 / 72, lt = r2 % 72;
    int c0 = ct * 32, l0 = lt * 32;
    int r = tid >> 5, cc = tid & 31;
    for (int rr = r; rr < 32; rr += 8)
      tile[rr][cc] = x[(size_t)bb * CIN * LL + (c0 + rr) * LL + l0 + cc];
    __syncthreads();
    for (int rr = r; rr < 32; rr += 8)
      xb[((size_t)bb * LL + l0 + rr) * CIN + c0 + cc] = f2bf(tile[cc][rr]);
  }
}

// ------- K2: in_proj bf16 MFMA + LN fold, LDS-staged coalesced epilogue ------
__global__ __launch_bounds__(256) void k_inprojM(const short* __restrict__ WgTb,
                                                 const short* __restrict__ xb,
                                                 const float* __restrict__ stats,
                                                 const float* __restrict__ sWg,
                                                 const float* __restrict__ sWb,
                                                 float* __restrict__ xin,
                                                 float* __restrict__ z) {
  __shared__ short As[64][40];
  __shared__ short Bs[64][40];
  __shared__ float ct[64][65];
  int n0 = blockIdx.x * 64;
  int m0 = blockIdx.y * 64;
  int tid = threadIdx.x;
  int lane = tid & 63;
  int wv = tid >> 6;
  int row16 = lane & 15;
  int kg = lane >> 4;
  int sm = tid >> 2;
  int sk8 = (tid & 3) * 8;
  f32x4 acc[4];
#pragma unroll
  for (int i = 0; i < 4; i++) acc[i] = (f32x4){0.f, 0.f, 0.f, 0.f};
#pragma unroll
  for (int ks = 0; ks < 96; ks += 32) {
    *(bf16x8*)&As[sm][sk8] = *(const bf16x8*)&WgTb[(size_t)(m0 + sm) * CIN + ks + sk8];
    *(bf16x8*)&Bs[sm][sk8] = *(const bf16x8*)&xb[(size_t)(n0 + sm) * CIN + ks + sk8];
    __syncthreads();
    bf16x8 a = *(const bf16x8*)&As[wv * 16 + row16][kg * 8];
#pragma unroll
    for (int tn = 0; tn < 4; tn++) {
      bf16x8 b = *(const bf16x8*)&Bs[tn * 16 + row16][kg * 8];
      acc[tn] = __builtin_amdgcn_mfma_f32_16x16x32_bf16(a, b, acc[tn], 0, 0, 0);
    }
    __syncthreads();
  }
#pragma unroll
  for (int tn = 0; tn < 4; tn++) {
    int nl = tn * 16 + row16;
    int mlb = wv * 16 + kg * 4;
#pragma unroll
    for (int i = 0; i < 4; i++) ct[mlb + i][nl] = acc[tn][i];
  }
  __syncthreads();
  if (m0 < DD) {
    for (int idx = tid; idx < 64 * 64; idx += 256) {
      int ml = idx >> 6, nl = idx & 63;
      int e = m0 + ml; int px = n0 + nl;
      int bb = px / LL, l = px - bb * LL;
      float mm = stats[px * 2], rr = stats[px * 2 + 1];
      float v = rr * (ct[ml][nl] - mm * sWg[e]) + sWb[e];
      xin[((size_t)bb * DD + e) * LL + l] = v;
    }
  } else {
    for (int idx = tid; idx < 64 * 64; idx += 256) {
      int nl = idx >> 6, ml = idx & 63;
      int e = m0 + ml; int px = n0 + nl;
      float mm = stats[px * 2], rr = stats[px * 2 + 1];
      float v = rr * (ct[ml][nl] - mm * sWg[e]) + sWb[e];
      z[(size_t)px * DD + (e - DD)] = v;
    }
  }
}

// ---------------- K3: depthwise 3x3 + silu -> xs (2 fp32 layouts) + xsb bf16 -
__global__ __launch_bounds__(256) void k_dwconv(const float* __restrict__ xin,
                                                const float* __restrict__ wdw,
                                                const float* __restrict__ bdw,
                                                float* __restrict__ xs,
                                                short* __restrict__ xsb) {
  __shared__ float vt[32 * 50];
  int bid = blockIdx.x;
  int bb = bid / 288; int r = bid % 288; int dg = r / 72; int tile = r % 72;
  int l0 = tile * 32;
  int d0 = dg * 48;
  for (int i = threadIdx.x; i < 32 * 48; i += 256) {
    int lj = i & 31, dl = i >> 5;
    int d = d0 + dl;
    int l = l0 + lj;
    int h = l / WW, w = l % WW;
    const float* xp = xin + (bb * DD + d) * LL;
    const float* wq = wdw + d * 9;
    float acc = bdw[d];
#pragma unroll
    for (int kh = 0; kh < 3; kh++) {
      int ih = h + kh - 1; if (ih < 0 || ih >= HH) continue;
#pragma unroll
      for (int kw = 0; kw < 3; kw++) {
        int iw = w + kw - 1; if (iw < 0 || iw >= WW) continue;
        acc += xp[ih * WW + iw] * wq[kh * 3 + kw];
      }
    }
    float v = acc / (1.f + __expf(-acc));
    vt[lj * 50 + dl] = v;
  }
  __syncthreads();
  for (int j = threadIdx.x; j < 32 * 48; j += 256) {
    int lj = j / 48, dl = j - lj * 48;
    int d = d0 + dl;
    int l = l0 + lj;
    int h = l / WW, w = l % WW;
    int lt = w * HH + h;
    float v = vt[lj * 50 + dl];
    xs[((size_t)(bb * 2 + 0) * LL + l) * DD + d] = v;
    xs[((size_t)(bb * 2 + 1) * LL + lt) * DD + d] = v;
    xsb[((size_t)bb * LL + l) * DD + d] = f2bf(v);
  }
}

// ------- K4: fused x_proj (bf16 MFMA) + dt/Bs/Cs split, per (dir, 64px) ------
__global__ __launch_bounds__(256) void k_xprojF(const short* __restrict__ At3p,
                                                const short* __restrict__ xsb,
                                                const float* __restrict__ dtw,
                                                const float* __restrict__ dtb,
                                                float* __restrict__ Bsb,
                                                float* __restrict__ Csb,
                                                float* __restrict__ delta) {
  __shared__ short As[48][40];
  __shared__ short Bs[64][40];
  __shared__ float ct[38][65];
  int bid = blockIdx.x;
  int kd = bid / 72; int tile = bid % 72;
  int pg0 = tile * 64;
  int bb = pg0 / LL;
  int lbase = pg0 - bb * LL;
  int tid = threadIdx.x;
  int lane = tid & 63;
  int wvn = tid >> 6;
  int row16 = lane & 15;
  int kg = lane >> 4;
  f32x4 acc[3];
#pragma unroll
  for (int j = 0; j < 3; j++) acc[j] = (f32x4){0.f, 0.f, 0.f, 0.f};
  int sm = tid >> 2, sk8 = (tid & 3) * 8;
  for (int ks = 0; ks < 192; ks += 32) {
    if (tid < 192)
      *(bf16x8*)&As[sm][sk8] =
          *(const bf16x8*)&At3p[(size_t)(kd * 48 + sm) * 192 + ks + sk8];
    *(bf16x8*)&Bs[sm][sk8] =
        *(const bf16x8*)&xsb[(size_t)(pg0 + sm) * 192 + ks + sk8];
    __syncthreads();
    bf16x8 b = *(const bf16x8*)&Bs[wvn * 16 + row16][kg * 8];
#pragma unroll
    for (int j = 0; j < 3; j++) {
      bf16x8 a = *(const bf16x8*)&As[j * 16 + row16][kg * 8];
      acc[j] = __builtin_amdgcn_mfma_f32_16x16x32_bf16(a, b, acc[j], 0, 0, 0);
    }
    __syncthreads();
  }
#pragma unroll
  for (int j = 0; j < 3; j++) {
    int rowb = j * 16 + kg * 4;
    int col = wvn * 16 + row16;
#pragma unroll
    for (int i = 0; i < 4; i++)
      if (rowb + i < 38) ct[rowb + i][col] = acc[j][i];
  }
  __syncthreads();
  for (int i = tid; i < 64 * 16; i += 256) {
    int lj = i >> 4, n = i & 15;
    int l = lbase + lj; int h = l / WW, w = l - h * WW; int lt = w * HH + h;
    int pos = (kd == 0) ? l : (kd == 1) ? lt : (kd == 2) ? (LL - 1 - l) : (LL - 1 - lt);
    size_t base = ((size_t)(bb * 4 + kd) * LL + pos) * NN + n;
    Bsb[base] = ct[6 + n][lj];
    Csb[base] = ct[22 + n][lj];
  }
  for (int i = tid; i < 64 * 192; i += 256) {
    int lj = i / 192, d = i - lj * 192;
    int l = lbase + lj; int h = l / WW, w = l - h * WW; int lt = w * HH + h;
    int pos = (kd == 0) ? l : (kd == 1) ? lt : (kd == 2) ? (LL - 1 - l) : (LL - 1 - lt);
    const float* wd = dtw + (kd * DD + d) * RR;
    float a2 = dtb[kd * DD + d];
#pragma unroll
    for (int r = 0; r < RR; r++) a2 += wd[r] * ct[r][lj];
    float sp = a2 > 20.f ? a2 : log1pf(__expf(a2));
    delta[((size_t)(bb * 4 + kd) * LL + pos) * DD + d] = sp;
  }
}

// ---------------- K5a: scan pass 1 -------------------------------------------
__global__ __launch_bounds__(192) void k_scan1(const float* __restrict__ delta,
                                               const float* __restrict__ xs,
                                               const float* __restrict__ Bsb,
                                               const float* __restrict__ A_logs,
                                               float* __restrict__ Pbuf,
                                               float* __restrict__ Sbuf) {
  __shared__ float Bls[LC * NN];
  int bid = blockIdx.x;
  int c = bid % NCH; int bk = bid / NCH; int k = bk & 3; int bb = bk >> 2;
  int t0 = c * LC;
  int d = threadIdx.x;
  const float* bp = Bsb + ((size_t)bk * LL + t0) * NN;
  for (int i = d; i < LC * NN; i += 192) Bls[i] = bp[i];
  float A[NN];
  {
    const float4* ap = (const float4*)(A_logs + (k * DD + d) * NN);
#pragma unroll
    for (int j = 0; j < 4; j++) {
      float4 a4 = ap[j];
      A[4 * j + 0] = -__expf(a4.x); A[4 * j + 1] = -__expf(a4.y);
      A[4 * j + 2] = -__expf(a4.z); A[4 * j + 3] = -__expf(a4.w);
    }
  }
  bool seq = true;
#pragma unroll
  for (int n = 0; n < NN; n++) seq = seq && (fabsf(A[n] + (float)(n + 1)) < 1e-3f);
  float h[NN];
#pragma unroll
  for (int n = 0; n < NN; n++) h[n] = 0.f;
  float sd = 0.f;
  __syncthreads();
  const float* dp = delta + ((size_t)bk * LL + t0) * DD + d;
  const float* xpb = xs + ((size_t)(bb * 2 + (k & 1)) * LL) * DD + d;
  const float* xp; int xstep;
  if (k < 2) { xp = xpb + (size_t)t0 * DD; xstep = DD; }
  else       { xp = xpb + (size_t)(LL - 1 - t0) * DD; xstep = -DD; }
#pragma unroll 2
  for (int t = 0; t < LC; ++t) {
    float dt = dp[t * DD];
    float xv = xp[t * xstep];
    float u = dt * xv;
    sd += dt;
    float dA[NN];
    if (seq) {
      float q = __expf(-dt);
      float q2 = q * q, q4 = q2 * q2, q8 = q4 * q4;
      dA[0] = q; dA[1] = q2; dA[2] = q2 * q; dA[3] = q4;
      dA[4] = q4 * q; dA[5] = q4 * q2; dA[6] = q4 * dA[2]; dA[7] = q8;
      dA[8] = q8 * q; dA[9] = q8 * q2; dA[10] = q8 * dA[2]; dA[11] = q8 * q4;
      dA[12] = q8 * dA[4]; dA[13] = q8 * dA[5]; dA[14] = q8 * dA[6]; dA[15] = q8 * q8;
    } else {
#pragma unroll
      for (int n = 0; n < NN; n++) dA[n] = __expf(dt * A[n]);
    }
    const float4* b4 = (const float4*)&Bls[t * NN];
#pragma unroll
    for (int j = 0; j < 4; j++) {
      float4 bv = b4[j];
      h[4 * j + 0] = dA[4 * j + 0] * h[4 * j + 0] + u * bv.x;
      h[4 * j + 1] = dA[4 * j + 1] * h[4 * j + 1] + u * bv.y;
      h[4 * j + 2] = dA[4 * j + 2] * h[4 * j + 2] + u * bv.z;
      h[4 * j + 3] = dA[4 * j + 3] * h[4 * j + 3] + u * bv.w;
    }
  }
  int chn = (bk * DD + d) * NN;
  float* pp = Pbuf + (size_t)c * 24576 + chn;
  float* sp = Sbuf + (size_t)c * 24576 + chn;
#pragma unroll
  for (int n = 0; n < NN; n++) { pp[n] = __expf(A[n] * sd); sp[n] = h[n]; }
}

// ---------------- K5b: combine chunks ----------------------------------------
__global__ __launch_bounds__(256) void k_scan2(const float* __restrict__ Pbuf,
                                               const float* __restrict__ Sbuf,
                                               float* __restrict__ Hinit) {
  int idx = blockIdx.x * 256 + threadIdx.x;
  float h = 0.f;
#pragma unroll 4
  for (int c = 0; c < NCH; c++) {
    Hinit[(size_t)c * 24576 + idx] = h;
    h = Pbuf[(size_t)c * 24576 + idx] * h + Sbuf[(size_t)c * 24576 + idx];
  }
}

// ---------------- K5c: scan pass 3 -------------------------------------------
__global__ __launch_bounds__(192) void k_scan3(const float* __restrict__ delta,
                                               const float* __restrict__ xs,
                                               const float* __restrict__ Bsb,
                                               const float* __restrict__ Csb,
                                               const float* __restrict__ A_logs,
                                               const float* __restrict__ Ds,
                                               const float* __restrict__ Hinit,
                                               float* __restrict__ ys) {
  __shared__ float Bls[LC * NN];
  __shared__ float Cls[LC * NN];
  int bid = blockIdx.x;
  int c = bid % NCH; int bk = bid / NCH; int k = bk & 3; int bb = bk >> 2;
  int t0 = c * LC;
  int d = threadIdx.x;
  const float* bp = Bsb + ((size_t)bk * LL + t0) * NN;
  const float* cp = Csb + ((size_t)bk * LL + t0) * NN;
  for (int i = d; i < LC * NN; i += 192) { Bls[i] = bp[i]; Cls[i] = cp[i]; }
  float A[NN];
  {
    const float4* ap = (const float4*)(A_logs + (k * DD + d) * NN);
#pragma unroll
    for (int j = 0; j < 4; j++) {
      float4 a4 = ap[j];
      A[4 * j + 0] = -__expf(a4.x); A[4 * j + 1] = -__expf(a4.y);
      A[4 * j + 2] = -__expf(a4.z); A[4 * j + 3] = -__expf(a4.w);
    }
  }
  bool seq = true;
#pragma unroll
  for (int n = 0; n < NN; n++) seq = seq && (fabsf(A[n] + (float)(n + 1)) < 1e-3f);
  float Dv = Ds[k * DD + d];
  float h[NN];
  {
    const float4* hp = (const float4*)(Hinit + (size_t)c * 24576 + (bk * DD + d) * NN);
#pragma unroll
    for (int j = 0; j < 4; j++) {
      float4 h4 = hp[j];
      h[4 * j + 0] = h4.x; h[4 * j + 1] = h4.y;
      h[4 * j + 2] = h4.z; h[4 * j + 3] = h4.w;
    }
  }
  __syncthreads();
  const float* dp = delta + ((size_t)bk * LL + t0) * DD + d;
  const float* xpb = xs + ((size_t)(bb * 2 + (k & 1)) * LL) * DD + d;
  const float* xp; int xstep;
  if (k < 2) { xp = xpb + (size_t)t0 * DD; xstep = DD; }
  else       { xp = xpb + (size_t)(LL - 1 - t0) * DD; xstep = -DD; }
  float* yp = ys + ((size_t)bk * LL + t0) * DD + d;
#pragma unroll 2
  for (int t = 0; t < LC; ++t) {
    float dt = dp[t * DD];
    float xv = xp[t * xstep];
    float u = dt * xv;
    float y = 0.f;
    float dA[NN];
    if (seq) {
      float q = __expf(-dt);
      float q2 = q * q, q4 = q2 * q2, q8 = q4 * q4;
      dA[0] = q; dA[1] = q2; dA[2] = q2 * q; dA[3] = q4;
      dA[4] = q4 * q; dA[5] = q4 * q2; dA[6] = q4 * dA[2]; dA[7] = q8;
      dA[8] = q8 * q; dA[9] = q8 * q2; dA[10] = q8 * dA[2]; dA[11] = q8 * q4;
      dA[12] = q8 * dA[4]; dA[13] = q8 * dA[5]; dA[14] = q8 * dA[6]; dA[15] = q8 * q8;
    } else {
#pragma unroll
      for (int n = 0; n < NN; n++) dA[n] = __expf(dt * A[n]);
    }
    const float4* b4 = (const float4*)&Bls[t * NN];
    const float4* c4 = (const float4*)&Cls[t * NN];
#pragma unroll
    for (int j = 0; j < 4; j++) {
      float4 bv = b4[j];
      float4 cc = c4[j];
      h[4 * j + 0] = dA[4 * j + 0] * h[4 * j + 0] + u * bv.x;
      h[4 * j + 1] = dA[4 * j + 1] * h[4 * j + 1] + u * bv.y;
      h[4 * j + 2] = dA[4 * j + 2] * h[4 * j + 2] + u * bv.z;
      h[4 * j + 3] = dA[4 * j + 3] * h[4 * j + 3] + u * bv.w;
      y += h[4 * j + 0] * cc.x + h[4 * j + 1] * cc.y
         + h[4 * j + 2] * cc.z + h[4 * j + 3] * cc.w;
    }
    yp[t * DD] = y + Dv * xv;
  }
}

// -------- K6: gather + out_norm LN + silu(z) + out_proj + residual -> xm -----
__global__ __launch_bounds__(256) void k_combineF(const float* __restrict__ ys,
                                                  const float* __restrict__ z,
                                                  const float* __restrict__ ong,
                                                  const float* __restrict__ onb,
                                                  const short* __restrict__ Wbf,
                                                  const float* __restrict__ x,
                                                  float* __restrict__ xm) {
  __shared__ float yt[16 * 194];
  __shared__ unsigned Wlu[96 * 98];
  int bx = blockIdx.x; int bb = bx / 144; int l0 = (bx % 144) * 16;
  int tid = threadIdx.x;
  const unsigned* Wu = (const unsigned*)Wbf;
  for (int i = tid; i < 96 * 96; i += 256) {
    int e = i / 96, d2 = i - e * 96;
    Wlu[e * 98 + d2] = Wu[i];
  }
  for (int i = tid; i < 16 * DD; i += 256) {
    int p = i / DD, d = i - p * DD;
    int l = l0 + p; int h = l / WW, w = l - h * WW;
    int t1 = w * HH + h;
    float v = ys[(((size_t)bb * KK + 0) * LL + l) * DD + d]
            + ys[(((size_t)bb * KK + 1) * LL + t1) * DD + d]
            + ys[(((size_t)bb * KK + 2) * LL + (LL - 1 - l)) * DD + d]
            + ys[(((size_t)bb * KK + 3) * LL + (LL - 1 - t1)) * DD + d];
    yt[p * 194 + d] = v;
  }
  __syncthreads();
  int p = tid >> 4, q = tid & 15;
  int l = l0 + p;
  float s = 0.f, ss = 0.f;
  for (int d = q * 12; d < q * 12 + 12; d++) { float v = yt[p * 194 + d]; s += v; ss += v * v; }
  s += __shfl_xor(s, 1, 64); s += __shfl_xor(s, 2, 64);
  s += __shfl_xor(s, 4, 64); s += __shfl_xor(s, 8, 64);
  ss += __shfl_xor(ss, 1, 64); ss += __shfl_xor(ss, 2, 64);
  ss += __shfl_xor(ss, 4, 64); ss += __shfl_xor(ss, 8, 64);
  float m = s / DD, var = ss / DD - m * m;
  float rr = rsqrtf(var + EPSF);
  const float* zp = z + (size_t)(bb * LL + l) * DD;
  for (int d = q * 12; d < q * 12 + 12; d++) {
    float v = (yt[p * 194 + d] - m) * rr * ong[d] + onb[d];
    float zv = zp[d];
    yt[p * 194 + d] = v * zv / (1.f + __expf(-zv));
  }
  __syncthreads();
  float acc[6];
#pragma unroll
  for (int j = 0; j < 6; j++) acc[j] = 0.f;
  for (int d2 = 0; d2 < 96; d2++) {
    float2 y2 = *(float2*)&yt[p * 194 + 2 * d2];
#pragma unroll
    for (int j = 0; j < 6; j++) {
      unsigned wv = Wlu[(q * 6 + j) * 98 + d2];
      float wlo = __uint_as_float(wv << 16);
      float whi = __uint_as_float(wv & 0xffff0000u);
      acc[j] += y2.x * wlo + y2.y * whi;
    }
  }
#pragma unroll
  for (int j = 0; j < 6; j++) {
    int e = q * 6 + j;
    size_t off = ((size_t)bb * CIN + e) * LL + l;
    xm[off] = x[off] + acc[j];
  }
}

// ------ K10m: bf16-MFMA conv GEMM, single-pass K, fused BN/PReLU epilogue ----
// EPI 1: conv1+2(+1x1): m<192 -> x2-BN; m<384 -> t3; m>=384 -> x1-BN
// EPI 2: conv3b: cc = 384+m, b33
template<int MT, int KTOT, int CI, int IH, int STRIDE, int EPI>
__global__ __launch_bounds__(256) void k_cgemm_mfma(const short* __restrict__ Abf,
                                                    const float* __restrict__ SRC,
                                                    float* __restrict__ out,
                                                    float* __restrict__ t3,
                                                    const float* __restrict__ b1,
                                                    const float* __restrict__ b31,
                                                    const float* __restrict__ b32,
                                                    const float* __restrict__ b33,
                                                    const float* __restrict__ bn_g,
                                                    const float* __restrict__ bn_b,
                                                    const float* __restrict__ bn_m,
                                                    const float* __restrict__ bn_v,
                                                    const float* __restrict__ prelu_a) {
  __shared__ short As[64][40];
  __shared__ short Bs[64][40];
  int n0 = blockIdx.x * 64;
  int m0 = blockIdx.y * 64;
  int tid = threadIdx.x;
  int lane = tid & 63;
  int wv = tid >> 6;
  int row16 = lane & 15;
  int kg = lane >> 4;
  int sm = tid >> 2;
  int sk8 = (tid & 3) * 8;
  int nS = n0 + sm;
  int bbS = nS / OHW; int remS = nS - bbS * OHW;
  int ohS = remS / OW, owS = remS - ohS * OW;
  f32x4 acc[4];
#pragma unroll
  for (int i = 0; i < 4; i++) acc[i] = (f32x4){0.f, 0.f, 0.f, 0.f};
  for (int ks = 0; ks < KTOT; ks += 32) {
    *(bf16x8*)&As[sm][sk8] =
        *(const bf16x8*)&Abf[(size_t)(m0 + sm) * KTOT + ks + sk8];
    bf16x8 bvv;
#pragma unroll
    for (int j = 0; j < 8; j++) {
      int k = ks + sk8 + j;
      int ci = k / 9; int r9 = k - ci * 9;
      int kh = r9 / 3, kw = r9 - kh * 3;
      int ih = STRIDE * ohS + kh - 1;
      int iw = STRIDE * owS + kw - 1;
      float v = (ih >= 0 && ih < IH && iw >= 0 && iw < IH)
              ? SRC[((size_t)(bbS * CI + ci) * IH + ih) * IH + iw] : 0.f;
      bvv[j] = f2bf(v);
    }
    *(bf16x8*)&Bs[sm][sk8] = bvv;
    __syncthreads();
    bf16x8 a = *(const bf16x8*)&As[wv * 16 + row16][kg * 8];
#pragma unroll
    for (int tn = 0; tn < 4; tn++) {
      bf16x8 b = *(const bf16x8*)&Bs[tn * 16 + row16][kg * 8];
      acc[tn] = __builtin_amdgcn_mfma_f32_16x16x32_bf16(a, b, acc[tn], 0, 0, 0);
    }
    __syncthreads();
  }
  float aslope = prelu_a[0];
#pragma unroll
  for (int tn = 0; tn < 4; tn++) {
    int n = n0 + tn * 16 + row16;
    int bb = n / OHW, o = n - bb * OHW;
    int rowb = m0 + wv * 16 + kg * 4;
#pragma unroll
    for (int i = 0; i < 4; i++) {
      int m = rowb + i;
      float s = acc[tn][i];
      if (EPI == 1) {
        if (m < 192) {
          int cc = 192 + m;
          s += b31[m];
          float scale = rsqrtf(bn_v[cc] + EPSF) * bn_g[cc];
          float v = s * scale + (bn_b[cc] - bn_m[cc] * scale);
          out[((size_t)bb * 576 + cc) * OHW + o] = v > 0.f ? v : aslope * v;
        } else if (m < 384) {
          t3[((size_t)bb * COUT + (m - 192)) * OHW + o] = s + b32[m - 192];
        } else {
          int cc = m - 384;
          s += b1[cc];
          float scale = rsqrtf(bn_v[cc] + EPSF) * bn_g[cc];
          float v = s * scale + (bn_b[cc] - bn_m[cc] * scale);
          out[((size_t)bb * 576 + cc) * OHW + o] = v > 0.f ? v : aslope * v;
        }
      } else {
        int cc = 384 + m;
        s += b33[m];
        float scale = rsqrtf(bn_v[cc] + EPSF) * bn_g[cc];
        float v = s * scale + (bn_b[cc] - bn_m[cc] * scale);
        out[((size_t)bb * 576 + cc) * OHW + o] = v > 0.f ? v : aslope * v;
      }
    }
  }
}

extern "C" void kernel_launch(void* const* d_in, const int* in_sizes, int n_in,
                              void* d_out, int out_size, void* d_ws, size_t ws_size,
                              hipStream_t stream) {
  const float* x        = (const float*)d_in[0];
  const float* ln_g     = (const float*)d_in[1];
  const float* ln_b     = (const float*)d_in[2];
  const float* in_proj_w= (const float*)d_in[3];
  const float* dwconv_w = (const float*)d_in[4];
  const float* dwconv_b = (const float*)d_in[5];
  const float* x_proj_w = (const float*)d_in[6];
  const float* dt_w     = (const float*)d_in[7];
  const float* dt_b     = (const float*)d_in[8];
  const float* A_logs   = (const float*)d_in[9];
  const float* Ds       = (const float*)d_in[10];
  const float* out_norm_g = (const float*)d_in[11];
  const float* out_norm_b = (const float*)d_in[12];
  const float* out_proj_w = (const float*)d_in[13];
  const float* w1  = (const float*)d_in[14];
  const float* b1  = (const float*)d_in[15];
  const float* w31 = (const float*)d_in[16];
  const float* b31 = (const float*)d_in[17];
  const float* w32 = (const float*)d_in[18];
  const float* b32 = (const float*)d_in[19];
  const float* w33 = (const float*)d_in[20];
  const float* b33 = (const float*)d_in[21];
  const float* bn_g = (const float*)d_in[22];
  const float* bn_b = (const float*)d_in[23];
  const float* bn_m = (const float*)d_in[24];
  const float* bn_v = (const float*)d_in[25];
  const float* prelu_a = (const float*)d_in[26];

  float* ws = (float*)d_ws;
  float* stats = ws + 0;           //   9216
  short* WgTb  = (short*)(ws + 16384);    //  36864 shorts
  float* sWg   = ws + 65536;       //    384
  float* sWb   = ws + 66048;       //    384
  short* At3p  = (short*)(ws + 98304);    //  36864 shorts
  short* At1b  = (short*)(ws + 147456);   // 497664 shorts
  short* At2b  = (short*)(ws + 397312);   // 331776 shorts
  short* woutb = (short*)(ws + 565248);   //  18432 shorts
  float* xin   = ws + 2097152;     // 884736
  float* z     = ws + 3145728;     // 884736
  float* xs    = ws + 4194304;     // 1769472
  short* xsb   = (short*)(ws + 6291456);  // 884736 shorts
  float* delta = ws + 10485760;    // 3538944
  float* Bsb   = ws + 14155776;    // 294912
  float* Csb   = ws + 14680064;    // 294912
  float* Pbuf  = ws + 15728640;    // 2359296
  float* Sbuf  = ws + 18874368;    // 2359296
  float* Hinit = ws + 22020096;    // 2359296
  float* ys    = ws + 25165824;    // 3538944
  float* xm    = ws + 29360128;    // 442368
  float* t3    = ws + 30408704;    // 221184
  short* xb    = (short*)(ws + 35651584); // 442368 shorts
  float* out = (float*)d_out;

  k_prep<<<3961, 256, 0, stream>>>(x, ln_g, ln_b, in_proj_w, x_proj_w,
                                   w31, w32, w33, w1, out_proj_w,
                                   stats, WgTb, sWg, sWb, At3p, At1b, At2b,
                                   woutb, xb);
  k_inprojM<<<dim3(72, 6), 256, 0, stream>>>(WgTb, xb, stats, sWg, sWb, xin, z);
  k_dwconv<<<576, 256, 0, stream>>>(xin, dwconv_w, dwconv_b, xs, xsb);
  k_xprojF<<<288, 256, 0, stream>>>(At3p, xsb, dt_w, dt_b, Bsb, Csb, delta);
  k_scan1<<<768, 192, 0, stream>>>(delta, xs, Bsb, A_logs, Pbuf, Sbuf);
  k_scan2<<<96, 256, 0, stream>>>(Pbuf, Sbuf, Hinit);
  k_scan3<<<768, 192, 0, stream>>>(delta, xs, Bsb, Csb, A_logs, Ds, Hinit, ys);
  k_combineF<<<288, 256, 0, stream>>>(ys, z, out_norm_g, out_norm_b, woutb, x, xm);
  // conv1+2 (+1x1): M=576, K=864, single-pass, fused BN/PReLU + t3
  k_cgemm_mfma<576, 864, CIN, HH, 2, 1><<<dim3(18, 9), 256, 0, stream>>>(
      At1b, xm, out, t3, b1, b31, b32, b33, bn_g, bn_b, bn_m, bn_v, prelu_a);
  // conv3b: M=192, K=1728, single-pass, fused BN/PReLU
  k_cgemm_mfma<192, 1728, COUT, OH, 1, 2><<<dim3(18, 3), 256, 0, stream>>>(
      At2b, t3, out, t3, b1, b31, b32, b33, bn_g, bn_b, bn_m, bn_v, prelu_a);
}

// Round 14
// 198.271 us; speedup vs baseline: 1.3049x; 1.3049x over previous
//
#include <hip/hip_runtime.h>
#include <math.h>

#define BB_ 2
#define HH 48
#define WW 48
#define LL 2304
#define CIN 96
#define DD 192
#define KK 4
#define NN 16
#define RR 6
#define NCH 96
#define LC 24
#define COUT 192
#define OH 24
#define OW 24
#define OHW 576
#define NPX 1152
#define NTOT 4608
#define EPSF 1e-5f

typedef __attribute__((ext_vector_type(8))) short bf16x8;
typedef __attribute__((ext_vector_type(4))) float f32x4;

__device__ __forceinline__ short f2bf(float f) {
  unsigned u = __float_as_uint(f);
  unsigned r = (u + 0x7fffu + ((u >> 16) & 1u)) >> 16;
  return (short)r;
}

// ---------------- K1: prep: LN stats, WgT, At3 (fp32), bf16 conv weights -----
__global__ __launch_bounds__(256) void k_prep(const float* __restrict__ x,
                                              const float* __restrict__ g,
                                              const float* __restrict__ b,
                                              const float* __restrict__ inw,
                                              const float* __restrict__ xpw,
                                              const float* __restrict__ w31,
                                              const float* __restrict__ w32,
                                              const float* __restrict__ w33,
                                              const float* __restrict__ w1,
                                              const float* __restrict__ wout,
                                              float* __restrict__ stats,
                                              float* __restrict__ WgT,
                                              float* __restrict__ sWg,
                                              float* __restrict__ sWb,
                                              float* __restrict__ At3,
                                              short* __restrict__ At1b,
                                              short* __restrict__ At2b,
                                              short* __restrict__ woutb) {
  int bx = blockIdx.x;
  int tid = threadIdx.x;
  if (bx < 72) {
    int bb = bx / 36; int l0 = (bx % 36) * 64;
    int p = tid >> 2, q = tid & 3;
    int l = l0 + p;
    const float* xp = x + bb * CIN * LL + l;
    float s = 0.f, ss = 0.f;
    for (int c = q; c < CIN; c += 4) { float v = xp[c * LL]; s += v; ss += v * v; }
    s += __shfl_xor(s, 1, 64); s += __shfl_xor(s, 2, 64);
    ss += __shfl_xor(ss, 1, 64); ss += __shfl_xor(ss, 2, 64);
    if (q == 0) {
      float m = s / CIN; float var = ss / CIN - m * m;
      stats[(bb * LL + l) * 2 + 0] = m;
      stats[(bb * LL + l) * 2 + 1] = rsqrtf(var + EPSF);
    }
  } else if (bx == 72) {
    for (int e = tid; e < 2 * DD; e += 256) {
      float swg = 0.f, swb = 0.f;
      for (int c = 0; c < CIN; c++) {
        float w = inw[e * CIN + c];
        float wg = w * g[c];
        WgT[c * 384 + e] = wg;
        swg += wg; swb += w * b[c];
      }
      sWg[e] = swg; sWb[e] = swb;
    }
  } else if (bx < 217) {
    int idx = (bx - 73) * 256 + tid;
    if (idx < 192 * 192) {
      int m = idx % 192, d = idx / 192;
      At3[idx] = (m < 152) ? xpw[m * 192 + d] : 0.f;
    }
  } else if (bx < 2161) {
    int i = (bx - 217) * 256 + tid;
    if (i < 497664) {                     // At1b[m][k], 576 x 864
      float v;
      if (i < 165888) v = w31[i];
      else if (i < 331776) v = w32[i - 165888];
      else {
        int k = i % 864; int m = i / 864 - 384;
        v = (k % 9 == 4) ? w1[m * 96 + k / 9] : 0.f;
      }
      At1b[i] = f2bf(v);
    }
  } else if (bx < 3457) {
    int i = (bx - 2161) * 256 + tid;
    if (i < 331776) At2b[i] = f2bf(w33[i]);  // At2b[m][k], 192 x 1728
  } else {
    int i = (bx - 3457) * 256 + tid;
    if (i < 18432) woutb[i] = f2bf(wout[i]); // [e=96][d=192]
  }
}

// ---------------- K3: depthwise 3x3 + silu -> xs (2 layouts) + xsl -----------
__global__ __launch_bounds__(256) void k_dwconv(const float* __restrict__ xin,
                                                const float* __restrict__ wdw,
                                                const float* __restrict__ bdw,
                                                float* __restrict__ xs,
                                                float* __restrict__ xsl) {
  __shared__ float vt[32 * 50];
  int bid = blockIdx.x;
  int bb = bid / 288; int r = bid % 288; int dg = r / 72; int tile = r % 72;
  int l0 = tile * 32;
  int d0 = dg * 48;
  for (int i = threadIdx.x; i < 32 * 48; i += 256) {
    int lj = i & 31, dl = i >> 5;
    int d = d0 + dl;
    int l = l0 + lj;
    int h = l / WW, w = l % WW;
    const float* xp = xin + (bb * DD + d) * LL;
    const float* wq = wdw + d * 9;
    float acc = bdw[d];
#pragma unroll
    for (int kh = 0; kh < 3; kh++) {
      int ih = h + kh - 1; if (ih < 0 || ih >= HH) continue;
#pragma unroll
      for (int kw = 0; kw < 3; kw++) {
        int iw = w + kw - 1; if (iw < 0 || iw >= WW) continue;
        acc += xp[ih * WW + iw] * wq[kh * 3 + kw];
      }
    }
    float v = acc / (1.f + __expf(-acc));
    vt[lj * 50 + dl] = v;
    xsl[(size_t)d * NTOT + bb * LL + l] = v;
  }
  __syncthreads();
  for (int j = threadIdx.x; j < 32 * 48; j += 256) {
    int lj = j / 48, dl = j - lj * 48;
    int d = d0 + dl;
    int l = l0 + lj;
    int h = l / WW, w = l % WW;
    int lt = w * HH + h;
    float v = vt[lj * 50 + dl];
    xs[((size_t)(bb * 2 + 0) * LL + l) * DD + d] = v;
    xs[((size_t)(bb * 2 + 1) * LL + lt) * DD + d] = v;
  }
}

// ---------------- K-dtsplit: C1 -> delta (softplus) + Bsb/Csb, permuted ------
__global__ __launch_bounds__(256) void k_dtsplit(const float* __restrict__ C1,
                                                 const float* __restrict__ dtw,
                                                 const float* __restrict__ dtb,
                                                 float* __restrict__ Bsb,
                                                 float* __restrict__ Csb,
                                                 float* __restrict__ delta) {
  __shared__ float lds[38 * 33];
  int bid = blockIdx.x;
  int tile = bid % 72; int bk = bid / 72; int bb = bk >> 2; int k = bk & 3;
  int l0 = tile * 32;
  int tid = threadIdx.x;
  for (int i = tid; i < 38 * 32; i += 256) {
    int r = i >> 5, lj = i & 31;
    lds[r * 33 + lj] = C1[(size_t)(k * 38 + r) * NTOT + bb * LL + l0 + lj];
  }
  __syncthreads();
  for (int i = tid; i < 32 * 16; i += 256) {
    int lj = i >> 4, n = i & 15;
    int l = l0 + lj; int h = l / WW, w = l % WW; int lt = w * HH + h;
    int pos = (k == 0) ? l : (k == 1) ? lt : (k == 2) ? (LL - 1 - l) : (LL - 1 - lt);
    size_t base = ((size_t)bk * LL + pos) * NN + n;
    Bsb[base] = lds[(6 + n) * 33 + lj];
    Csb[base] = lds[(22 + n) * 33 + lj];
  }
  for (int i = tid; i < 32 * 192; i += 256) {
    int lj = i / 192, d = i - lj * 192;
    int l = l0 + lj; int h = l / WW, w = l % WW; int lt = w * HH + h;
    int pos = (k == 0) ? l : (k == 1) ? lt : (k == 2) ? (LL - 1 - l) : (LL - 1 - lt);
    const float* wd = dtw + (k * DD + d) * RR;
    float acc = dtb[k * DD + d];
#pragma unroll
    for (int r = 0; r < RR; r++) acc += wd[r] * lds[r * 33 + lj];
    float sp = acc > 20.f ? acc : log1pf(__expf(acc));
    delta[((size_t)bk * LL + pos) * DD + d] = sp;
  }
}

// ---------------- K5a: scan pass 1 -------------------------------------------
__global__ __launch_bounds__(192) void k_scan1(const float* __restrict__ delta,
                                               const float* __restrict__ xs,
                                               const float* __restrict__ Bsb,
                                               const float* __restrict__ A_logs,
                                               float* __restrict__ Pbuf,
                                               float* __restrict__ Sbuf) {
  __shared__ float Bls[LC * NN];
  int bid = blockIdx.x;
  int c = bid % NCH; int bk = bid / NCH; int k = bk & 3; int bb = bk >> 2;
  int t0 = c * LC;
  int d = threadIdx.x;
  const float* bp = Bsb + ((size_t)bk * LL + t0) * NN;
  for (int i = d; i < LC * NN; i += 192) Bls[i] = bp[i];
  float A[NN];
  {
    const float4* ap = (const float4*)(A_logs + (k * DD + d) * NN);
#pragma unroll
    for (int j = 0; j < 4; j++) {
      float4 a4 = ap[j];
      A[4 * j + 0] = -__expf(a4.x); A[4 * j + 1] = -__expf(a4.y);
      A[4 * j + 2] = -__expf(a4.z); A[4 * j + 3] = -__expf(a4.w);
    }
  }
  bool seq = true;
#pragma unroll
  for (int n = 0; n < NN; n++) seq = seq && (fabsf(A[n] + (float)(n + 1)) < 1e-3f);
  float h[NN];
#pragma unroll
  for (int n = 0; n < NN; n++) h[n] = 0.f;
  float sd = 0.f;
  __syncthreads();
  const float* dp = delta + ((size_t)bk * LL + t0) * DD + d;
  const float* xpb = xs + ((size_t)(bb * 2 + (k & 1)) * LL) * DD + d;
  const float* xp; int xstep;
  if (k < 2) { xp = xpb + (size_t)t0 * DD; xstep = DD; }
  else       { xp = xpb + (size_t)(LL - 1 - t0) * DD; xstep = -DD; }
#pragma unroll 2
  for (int t = 0; t < LC; ++t) {
    float dt = dp[t * DD];
    float xv = xp[t * xstep];
    float u = dt * xv;
    sd += dt;
    float dA[NN];
    if (seq) {
      float q = __expf(-dt);
      float q2 = q * q, q4 = q2 * q2, q8 = q4 * q4;
      dA[0] = q; dA[1] = q2; dA[2] = q2 * q; dA[3] = q4;
      dA[4] = q4 * q; dA[5] = q4 * q2; dA[6] = q4 * dA[2]; dA[7] = q8;
      dA[8] = q8 * q; dA[9] = q8 * q2; dA[10] = q8 * dA[2]; dA[11] = q8 * q4;
      dA[12] = q8 * dA[4]; dA[13] = q8 * dA[5]; dA[14] = q8 * dA[6]; dA[15] = q8 * q8;
    } else {
#pragma unroll
      for (int n = 0; n < NN; n++) dA[n] = __expf(dt * A[n]);
    }
    const float4* b4 = (const float4*)&Bls[t * NN];
#pragma unroll
    for (int j = 0; j < 4; j++) {
      float4 bv = b4[j];
      h[4 * j + 0] = dA[4 * j + 0] * h[4 * j + 0] + u * bv.x;
      h[4 * j + 1] = dA[4 * j + 1] * h[4 * j + 1] + u * bv.y;
      h[4 * j + 2] = dA[4 * j + 2] * h[4 * j + 2] + u * bv.z;
      h[4 * j + 3] = dA[4 * j + 3] * h[4 * j + 3] + u * bv.w;
    }
  }
  int chn = (bk * DD + d) * NN;
  float* pp = Pbuf + (size_t)c * 24576 + chn;
  float* sp = Sbuf + (size_t)c * 24576 + chn;
#pragma unroll
  for (int n = 0; n < NN; n++) { pp[n] = __expf(A[n] * sd); sp[n] = h[n]; }
}

// ---------------- K5b: combine chunks ----------------------------------------
__global__ __launch_bounds__(256) void k_scan2(const float* __restrict__ Pbuf,
                                               const float* __restrict__ Sbuf,
                                               float* __restrict__ Hinit) {
  int idx = blockIdx.x * 256 + threadIdx.x;
  float h = 0.f;
#pragma unroll 4
  for (int c = 0; c < NCH; c++) {
    Hinit[(size_t)c * 24576 + idx] = h;
    h = Pbuf[(size_t)c * 24576 + idx] * h + Sbuf[(size_t)c * 24576 + idx];
  }
}

// ---------------- K5c: scan pass 3 -------------------------------------------
__global__ __launch_bounds__(192) void k_scan3(const float* __restrict__ delta,
                                               const float* __restrict__ xs,
                                               const float* __restrict__ Bsb,
                                               const float* __restrict__ Csb,
                                               const float* __restrict__ A_logs,
                                               const float* __restrict__ Ds,
                                               const float* __restrict__ Hinit,
                                               float* __restrict__ ys) {
  __shared__ float Bls[LC * NN];
  __shared__ float Cls[LC * NN];
  int bid = blockIdx.x;
  int c = bid % NCH; int bk = bid / NCH; int k = bk & 3; int bb = bk >> 2;
  int t0 = c * LC;
  int d = threadIdx.x;
  const float* bp = Bsb + ((size_t)bk * LL + t0) * NN;
  const float* cp = Csb + ((size_t)bk * LL + t0) * NN;
  for (int i = d; i < LC * NN; i += 192) { Bls[i] = bp[i]; Cls[i] = cp[i]; }
  float A[NN];
  {
    const float4* ap = (const float4*)(A_logs + (k * DD + d) * NN);
#pragma unroll
    for (int j = 0; j < 4; j++) {
      float4 a4 = ap[j];
      A[4 * j + 0] = -__expf(a4.x); A[4 * j + 1] = -__expf(a4.y);
      A[4 * j + 2] = -__expf(a4.z); A[4 * j + 3] = -__expf(a4.w);
    }
  }
  bool seq = true;
#pragma unroll
  for (int n = 0; n < NN; n++) seq = seq && (fabsf(A[n] + (float)(n + 1)) < 1e-3f);
  float Dv = Ds[k * DD + d];
  float h[NN];
  {
    const float4* hp = (const float4*)(Hinit + (size_t)c * 24576 + (bk * DD + d) * NN);
#pragma unroll
    for (int j = 0; j < 4; j++) {
      float4 h4 = hp[j];
      h[4 * j + 0] = h4.x; h[4 * j + 1] = h4.y;
      h[4 * j + 2] = h4.z; h[4 * j + 3] = h4.w;
    }
  }
  __syncthreads();
  const float* dp = delta + ((size_t)bk * LL + t0) * DD + d;
  const float* xpb = xs + ((size_t)(bb * 2 + (k & 1)) * LL) * DD + d;
  const float* xp; int xstep;
  if (k < 2) { xp = xpb + (size_t)t0 * DD; xstep = DD; }
  else       { xp = xpb + (size_t)(LL - 1 - t0) * DD; xstep = -DD; }
  float* yp = ys + ((size_t)bk * LL + t0) * DD + d;
#pragma unroll 2
  for (int t = 0; t < LC; ++t) {
    float dt = dp[t * DD];
    float xv = xp[t * xstep];
    float u = dt * xv;
    float y = 0.f;
    float dA[NN];
    if (seq) {
      float q = __expf(-dt);
      float q2 = q * q, q4 = q2 * q2, q8 = q4 * q4;
      dA[0] = q; dA[1] = q2; dA[2] = q2 * q; dA[3] = q4;
      dA[4] = q4 * q; dA[5] = q4 * q2; dA[6] = q4 * dA[2]; dA[7] = q8;
      dA[8] = q8 * q; dA[9] = q8 * q2; dA[10] = q8 * dA[2]; dA[11] = q8 * q4;
      dA[12] = q8 * dA[4]; dA[13] = q8 * dA[5]; dA[14] = q8 * dA[6]; dA[15] = q8 * q8;
    } else {
#pragma unroll
      for (int n = 0; n < NN; n++) dA[n] = __expf(dt * A[n]);
    }
    const float4* b4 = (const float4*)&Bls[t * NN];
    const float4* c4 = (const float4*)&Cls[t * NN];
#pragma unroll
    for (int j = 0; j < 4; j++) {
      float4 bv = b4[j];
      float4 cc = c4[j];
      h[4 * j + 0] = dA[4 * j + 0] * h[4 * j + 0] + u * bv.x;
      h[4 * j + 1] = dA[4 * j + 1] * h[4 * j + 1] + u * bv.y;
      h[4 * j + 2] = dA[4 * j + 2] * h[4 * j + 2] + u * bv.z;
      h[4 * j + 3] = dA[4 * j + 3] * h[4 * j + 3] + u * bv.w;
      y += h[4 * j + 0] * cc.x + h[4 * j + 1] * cc.y
         + h[4 * j + 2] * cc.z + h[4 * j + 3] * cc.w;
    }
    yp[t * DD] = y + Dv * xv;
  }
}

// -------- K6: gather + out_norm LN + silu(z) + out_proj + residual -> xm -----
__global__ __launch_bounds__(256) void k_combineF(const float* __restrict__ ys,
                                                  const float* __restrict__ z,
                                                  const float* __restrict__ ong,
                                                  const float* __restrict__ onb,
                                                  const short* __restrict__ Wbf,
                                                  const float* __restrict__ x,
                                                  float* __restrict__ xm) {
  __shared__ float yt[32 * 194];
  __shared__ unsigned Wlu[96 * 98];
  int bx = blockIdx.x; int bb = bx / 72; int l0 = (bx % 72) * 32;
  int tid = threadIdx.x;
  const unsigned* Wu = (const unsigned*)Wbf;
  for (int i = tid; i < 96 * 96; i += 256) {
    int e = i / 96, d2 = i - e * 96;
    Wlu[e * 98 + d2] = Wu[i];
  }
  for (int i = tid; i < 32 * DD; i += 256) {
    int p = i / DD, d = i - p * DD;
    int l = l0 + p; int h = l / WW, w = l - h * WW;
    int t1 = w * HH + h;
    float v = ys[(((size_t)bb * KK + 0) * LL + l) * DD + d]
            + ys[(((size_t)bb * KK + 1) * LL + t1) * DD + d]
            + ys[(((size_t)bb * KK + 2) * LL + (LL - 1 - l)) * DD + d]
            + ys[(((size_t)bb * KK + 3) * LL + (LL - 1 - t1)) * DD + d];
    yt[p * 194 + d] = v;
  }
  __syncthreads();
  int p = tid >> 3, q = tid & 7;
  int l = l0 + p;
  float s = 0.f, ss = 0.f;
  for (int d = q * 24; d < q * 24 + 24; d++) { float v = yt[p * 194 + d]; s += v; ss += v * v; }
  s += __shfl_xor(s, 1, 64); s += __shfl_xor(s, 2, 64); s += __shfl_xor(s, 4, 64);
  ss += __shfl_xor(ss, 1, 64); ss += __shfl_xor(ss, 2, 64); ss += __shfl_xor(ss, 4, 64);
  float m = s / DD, var = ss / DD - m * m;
  float rr = rsqrtf(var + EPSF);
  const float* zp = z + (size_t)(bb * LL + l) * DD;
  for (int d = q * 24; d < q * 24 + 24; d++) {
    float v = (yt[p * 194 + d] - m) * rr * ong[d] + onb[d];
    float zv = zp[d];
    yt[p * 194 + d] = v * zv / (1.f + __expf(-zv));
  }
  __syncthreads();
  float acc[12];
#pragma unroll
  for (int j = 0; j < 12; j++) acc[j] = 0.f;
  for (int d2 = 0; d2 < 96; d2++) {
    float2 y2 = *(float2*)&yt[p * 194 + 2 * d2];
#pragma unroll
    for (int j = 0; j < 12; j++) {
      unsigned wv = Wlu[(q * 12 + j) * 98 + d2];
      float wlo = __uint_as_float(wv << 16);
      float whi = __uint_as_float(wv & 0xffff0000u);
      acc[j] += y2.x * wlo + y2.y * whi;
    }
  }
#pragma unroll
  for (int j = 0; j < 12; j++) {
    int e = q * 12 + j;
    size_t off = ((size_t)bb * CIN + e) * LL + l;
    xm[off] = x[off] + acc[j];
  }
}

// ---------------- K10: plain fp32 tiled GEMM (x_proj) ------------------------
template<int MT, int KCHUNK, int NB>
__global__ __launch_bounds__(256) void k_gemm(const float* __restrict__ At,
                                              const float* __restrict__ Bm,
                                              float* __restrict__ Cout) {
  __shared__ float As[16][64];
  __shared__ float Bs[16][64];
  int n0 = blockIdx.x * 64;
  int m0 = blockIdx.y * 64;
  int kz = blockIdx.z;
  int k0 = kz * KCHUNK;
  int tid = threadIdx.x;
  int lr = tid >> 4;
  int lc = (tid & 15) * 4;
  int tm = tid >> 4;
  int tn = tid & 15;
  float acc[4][4] = {};
  for (int ks = 0; ks < KCHUNK; ks += 16) {
    int kg = k0 + ks + lr;
    *(float4*)&As[lr][lc] = *(const float4*)&At[kg * MT + m0 + lc];
    *(float4*)&Bs[lr][lc] = *(const float4*)&Bm[(size_t)kg * NB + n0 + lc];
    __syncthreads();
#pragma unroll
    for (int kk = 0; kk < 16; kk++) {
      float4 a = *(float4*)&As[kk][tm * 4];
      float4 b = *(float4*)&Bs[kk][tn * 4];
      acc[0][0] += a.x * b.x; acc[0][1] += a.x * b.y; acc[0][2] += a.x * b.z; acc[0][3] += a.x * b.w;
      acc[1][0] += a.y * b.x; acc[1][1] += a.y * b.y; acc[1][2] += a.y * b.z; acc[1][3] += a.y * b.w;
      acc[2][0] += a.z * b.x; acc[2][1] += a.z * b.y; acc[2][2] += a.z * b.z; acc[2][3] += a.z * b.w;
      acc[3][0] += a.w * b.x; acc[3][1] += a.w * b.y; acc[3][2] += a.w * b.z; acc[3][3] += a.w * b.w;
    }
    __syncthreads();
  }
  float* cp = Cout + ((size_t)kz * MT + m0) * NB + n0;
#pragma unroll
  for (int i = 0; i < 4; i++) {
    float4 v = {acc[i][0], acc[i][1], acc[i][2], acc[i][3]};
    *(float4*)&cp[(size_t)(tm * 4 + i) * NB + tn * 4] = v;
  }
}

// ---------------- K10m: bf16-MFMA conv GEMM with fused im2col, split-K -------
template<int MT, int KTOT, int KCHUNK, int CI, int IH, int STRIDE>
__global__ __launch_bounds__(256) void k_cgemm_mfma(const short* __restrict__ Abf,
                                                    const float* __restrict__ SRC,
                                                    float* __restrict__ Cout) {
  __shared__ short As[64][40];
  __shared__ short Bs[64][40];
  int n0 = blockIdx.x * 64;
  int m0 = blockIdx.y * 64;
  int kz = blockIdx.z;
  int k0 = kz * KCHUNK;
  int tid = threadIdx.x;
  int lane = tid & 63;
  int wv = tid >> 6;
  int row16 = lane & 15;
  int kg = lane >> 4;
  int sm = tid >> 2;
  int sk8 = (tid & 3) * 8;
  int n = n0 + sm;
  int bb = n / OHW; int rem = n - bb * OHW;
  int oh = rem / OW, ow = rem - oh * OW;
  f32x4 acc[4];
#pragma unroll
  for (int i = 0; i < 4; i++) acc[i] = (f32x4){0.f, 0.f, 0.f, 0.f};
  for (int ks = 0; ks < KCHUNK; ks += 32) {
    *(bf16x8*)&As[sm][sk8] =
        *(const bf16x8*)&Abf[(size_t)(m0 + sm) * KTOT + k0 + ks + sk8];
    bf16x8 bvv;
#pragma unroll
    for (int j = 0; j < 8; j++) {
      int k = k0 + ks + sk8 + j;
      int ci = k / 9; int r9 = k - ci * 9;
      int kh = r9 / 3, kw = r9 - kh * 3;
      int ih = STRIDE * oh + kh - 1;
      int iw = STRIDE * ow + kw - 1;
      float v = (ih >= 0 && ih < IH && iw >= 0 && iw < IH)
              ? SRC[((size_t)(bb * CI + ci) * IH + ih) * IH + iw] : 0.f;
      bvv[j] = f2bf(v);
    }
    *(bf16x8*)&Bs[sm][sk8] = bvv;
    __syncthreads();
    bf16x8 a = *(const bf16x8*)&As[wv * 16 + row16][kg * 8];
#pragma unroll
    for (int tn = 0; tn < 4; tn++) {
      bf16x8 b = *(const bf16x8*)&Bs[tn * 16 + row16][kg * 8];
      acc[tn] = __builtin_amdgcn_mfma_f32_16x16x32_bf16(a, b, acc[tn], 0, 0, 0);
    }
    __syncthreads();
  }
#pragma unroll
  for (int tn = 0; tn < 4; tn++) {
    int col = n0 + tn * 16 + row16;
    int rowb = m0 + wv * 16 + kg * 4;
#pragma unroll
    for (int i = 0; i < 4; i++)
      Cout[((size_t)kz * MT + rowb + i) * NPX + col] = acc[tn][i];
  }
}

// ---------------- K10F: per-batch fp32 GEMM, LN-folded in_proj epilogue ------
template<int MT, int KD>
__global__ __launch_bounds__(256) void k_gemmF(const float* __restrict__ At,
                                               const float* __restrict__ Bm,
                                               int ldb, int boffB,
                                               float* __restrict__ C0,
                                               int ldc, int boffC,
                                               const float* __restrict__ a0,
                                               const float* __restrict__ a1,
                                               const float* __restrict__ a2,
                                               float* __restrict__ a3) {
  __shared__ float As[16][64];
  __shared__ float Bs[16][64];
  int n0 = blockIdx.x * 64;
  int m0 = blockIdx.y * 64;
  int bb = blockIdx.z;
  const float* B = Bm + (size_t)bb * boffB;
  int tid = threadIdx.x;
  int lr = tid >> 4;
  int lc = (tid & 15) * 4;
  int tm = tid >> 4;
  int tn = tid & 15;
  float acc[4][4] = {};
  for (int ks = 0; ks < KD; ks += 16) {
    *(float4*)&As[lr][lc] = *(const float4*)&At[(ks + lr) * MT + m0 + lc];
    *(float4*)&Bs[lr][lc] = *(const float4*)&B[(size_t)(ks + lr) * ldb + n0 + lc];
    __syncthreads();
#pragma unroll
    for (int kk = 0; kk < 16; kk++) {
      float4 a = *(float4*)&As[kk][tm * 4];
      float4 b = *(float4*)&Bs[kk][tn * 4];
      acc[0][0] += a.x * b.x; acc[0][1] += a.x * b.y; acc[0][2] += a.x * b.z; acc[0][3] += a.x * b.w;
      acc[1][0] += a.y * b.x; acc[1][1] += a.y * b.y; acc[1][2] += a.y * b.z; acc[1][3] += a.y * b.w;
      acc[2][0] += a.z * b.x; acc[2][1] += a.z * b.y; acc[2][2] += a.z * b.z; acc[2][3] += a.z * b.w;
      acc[3][0] += a.w * b.x; acc[3][1] += a.w * b.y; acc[3][2] += a.w * b.z; acc[3][3] += a.w * b.w;
    }
    __syncthreads();
  }
  int n = n0 + tn * 4;
  float m_[4], r_[4];
#pragma unroll
  for (int j = 0; j < 4; j++) {
    m_[j] = a0[((size_t)bb * LL + n + j) * 2];
    r_[j] = a0[((size_t)bb * LL + n + j) * 2 + 1];
  }
#pragma unroll
  for (int i = 0; i < 4; i++) {
    int e = m0 + tm * 4 + i;
    float swg = a1[e], swb = a2[e];
    float v0 = r_[0] * (acc[i][0] - m_[0] * swg) + swb;
    float v1 = r_[1] * (acc[i][1] - m_[1] * swg) + swb;
    float v2 = r_[2] * (acc[i][2] - m_[2] * swg) + swb;
    float v3 = r_[3] * (acc[i][3] - m_[3] * swg) + swb;
    if (e < DD) {
      float4 v = {v0, v1, v2, v3};
      *(float4*)&C0[(size_t)bb * boffC + (size_t)e * ldc + n] = v;
    } else {
      a3[((size_t)bb * LL + n + 0) * DD + (e - DD)] = v0;
      a3[((size_t)bb * LL + n + 1) * DD + (e - DD)] = v1;
      a3[((size_t)bb * LL + n + 2) * DD + (e - DD)] = v2;
      a3[((size_t)bb * LL + n + 3) * DD + (e - DD)] = v3;
    }
  }
}

// ---------------- K11: reduce split-K (3): x2-BN / t3 / x1-BN ----------------
__global__ __launch_bounds__(256) void k_reduce1(const float* __restrict__ Cp1,
                                                 const float* __restrict__ b1,
                                                 const float* __restrict__ b31,
                                                 const float* __restrict__ b32,
                                                 const float* __restrict__ bn_g,
                                                 const float* __restrict__ bn_b,
                                                 const float* __restrict__ bn_m,
                                                 const float* __restrict__ bn_v,
                                                 const float* __restrict__ prelu_a,
                                                 float* __restrict__ out,
                                                 float* __restrict__ t3) {
  int idx = blockIdx.x * 256 + threadIdx.x;
  if (idx >= 576 * NPX) return;
  int m = idx / NPX, n = idx % NPX;
  float s = 0.f;
#pragma unroll
  for (int c = 0; c < 3; c++) s += Cp1[(size_t)c * 576 * NPX + idx];
  int bb = n / OHW, o = n % OHW;
  if (m < 192) {
    s += b31[m];
    int cc = 192 + m;
    float scale = rsqrtf(bn_v[cc] + EPSF) * bn_g[cc];
    float v = s * scale + (bn_b[cc] - bn_m[cc] * scale);
    float a = prelu_a[0];
    out[((size_t)bb * 576 + cc) * OHW + o] = v > 0.f ? v : a * v;
  } else if (m < 384) {
    s += b32[m - 192];
    t3[((size_t)bb * COUT + (m - 192)) * OHW + o] = s;
  } else {
    s += b1[m - 384];
    int cc = m - 384;
    float scale = rsqrtf(bn_v[cc] + EPSF) * bn_g[cc];
    float v = s * scale + (bn_b[cc] - bn_m[cc] * scale);
    float a = prelu_a[0];
    out[((size_t)bb * 576 + cc) * OHW + o] = v > 0.f ? v : a * v;
  }
}

// ---------------- K12: reduce split-K (6) w33 -> out x3 w/ BN ----------------
__global__ __launch_bounds__(256) void k_reduce2(const float* __restrict__ Cp2,
                                                 const float* __restrict__ b33,
                                                 const float* __restrict__ bn_g,
                                                 const float* __restrict__ bn_b,
                                                 const float* __restrict__ bn_m,
                                                 const float* __restrict__ bn_v,
                                                 const float* __restrict__ prelu_a,
                                                 float* __restrict__ out) {
  int idx = blockIdx.x * 256 + threadIdx.x;
  if (idx >= 192 * NPX) return;
  int m = idx / NPX, n = idx % NPX;
  float s = b33[m];
#pragma unroll
  for (int c = 0; c < 6; c++) s += Cp2[(size_t)c * 192 * NPX + idx];
  int bb = n / OHW, o = n % OHW;
  int cc = 384 + m;
  float scale = rsqrtf(bn_v[cc] + EPSF) * bn_g[cc];
  float v = s * scale + (bn_b[cc] - bn_m[cc] * scale);
  float a = prelu_a[0];
  out[((size_t)bb * 576 + cc) * OHW + o] = v > 0.f ? v : a * v;
}

extern "C" void kernel_launch(void* const* d_in, const int* in_sizes, int n_in,
                              void* d_out, int out_size, void* d_ws, size_t ws_size,
                              hipStream_t stream) {
  const float* x        = (const float*)d_in[0];
  const float* ln_g     = (const float*)d_in[1];
  const float* ln_b     = (const float*)d_in[2];
  const float* in_proj_w= (const float*)d_in[3];
  const float* dwconv_w = (const float*)d_in[4];
  const float* dwconv_b = (const float*)d_in[5];
  const float* x_proj_w = (const float*)d_in[6];
  const float* dt_w     = (const float*)d_in[7];
  const float* dt_b     = (const float*)d_in[8];
  const float* A_logs   = (const float*)d_in[9];
  const float* Ds       = (const float*)d_in[10];
  const float* out_norm_g = (const float*)d_in[11];
  const float* out_norm_b = (const float*)d_in[12];
  const float* out_proj_w = (const float*)d_in[13];
  const float* w1  = (const float*)d_in[14];
  const float* b1  = (const float*)d_in[15];
  const float* w31 = (const float*)d_in[16];
  const float* b31 = (const float*)d_in[17];
  const float* w32 = (const float*)d_in[18];
  const float* b32 = (const float*)d_in[19];
  const float* w33 = (const float*)d_in[20];
  const float* b33 = (const float*)d_in[21];
  const float* bn_g = (const float*)d_in[22];
  const float* bn_b = (const float*)d_in[23];
  const float* bn_m = (const float*)d_in[24];
  const float* bn_v = (const float*)d_in[25];
  const float* prelu_a = (const float*)d_in[26];

  float* ws = (float*)d_ws;
  float* stats = ws + 0;           //   9216
  float* WgT   = ws + 16384;       //  36864
  float* sWg   = ws + 65536;       //    384
  float* sWb   = ws + 66048;       //    384
  float* At3   = ws + 98304;       //  36864
  short* At1b  = (short*)(ws + 147456);   // 497664 shorts
  short* At2b  = (short*)(ws + 397312);   // 331776 shorts
  short* woutb = (short*)(ws + 565248);   //  18432 shorts
  float* xin   = ws + 2097152;     // 884736
  float* z     = ws + 3145728;     // 884736
  float* xs    = ws + 4194304;     // 1769472
  float* xsl   = ws + 8388608;     // 884736
  float* C1    = ws + 9437184;     // 884736
  float* delta = ws + 10485760;    // 3538944
  float* Bsb   = ws + 14155776;    // 294912
  float* Csb   = ws + 14680064;    // 294912
  float* Pbuf  = ws + 15728640;    // 2359296
  float* Sbuf  = ws + 18874368;    // 2359296
  float* Hinit = ws + 22020096;    // 2359296
  float* ys    = ws + 25165824;    // 3538944
  float* xm    = ws + 29360128;    // 442368
  float* t3    = ws + 30408704;    // 221184
  float* Cp1   = ws + 31457280;    // 1990656 (3 x 576 x 1152)
  float* Cp2   = ws + 33554432;    // 1327104 (6 x 192 x 1152)
  float* out = (float*)d_out;

  k_prep<<<3529, 256, 0, stream>>>(x, ln_g, ln_b, in_proj_w, x_proj_w,
                                   w31, w32, w33, w1, out_proj_w,
                                   stats, WgT, sWg, sWb, At3, At1b, At2b, woutb);
  k_gemmF<384, 96><<<dim3(36, 6, 2), 256, 0, stream>>>(
      WgT, x, LL, CIN * LL, xin, LL, DD * LL, stats, sWg, sWb, z);
  k_dwconv<<<576, 256, 0, stream>>>(xin, dwconv_w, dwconv_b, xs, xsl);
  k_gemm<192, 192, NTOT><<<dim3(72, 3, 1), 256, 0, stream>>>(At3, xsl, C1);
  k_dtsplit<<<576, 256, 0, stream>>>(C1, dt_w, dt_b, Bsb, Csb, delta);
  k_scan1<<<768, 192, 0, stream>>>(delta, xs, Bsb, A_logs, Pbuf, Sbuf);
  k_scan2<<<96, 256, 0, stream>>>(Pbuf, Sbuf, Hinit);
  k_scan3<<<768, 192, 0, stream>>>(delta, xs, Bsb, Csb, A_logs, Ds, Hinit, ys);
  k_combineF<<<144, 256, 0, stream>>>(ys, z, out_norm_g, out_norm_b, woutb, x, xm);
  // conv1+2 (+1x1): M=576, K=864, split-K 3, bf16 MFMA
  k_cgemm_mfma<576, 864, 288, CIN, HH, 2><<<dim3(18, 9, 3), 256, 0, stream>>>(
      At1b, xm, Cp1);
  k_reduce1<<<2592, 256, 0, stream>>>(Cp1, b1, b31, b32, bn_g, bn_b, bn_m, bn_v,
                                      prelu_a, out, t3);
  // conv3b: M=192, K=1728, split-K 6, bf16 MFMA
  k_cgemm_mfma<192, 1728, 288, COUT, OH, 1><<<dim3(18, 3, 6), 256, 0, stream>>>(
      At2b, t3, Cp2);
  k_reduce2<<<864, 256, 0, stream>>>(Cp2, b33, bn_g, bn_b, bn_m, bn_v, prelu_a, out);
}

// Round 15
// 190.643 us; speedup vs baseline: 1.3571x; 1.0400x over previous
//
#include <hip/hip_runtime.h>
#include <math.h>

#define BB_ 2
#define HH 48
#define WW 48
#define LL 2304
#define CIN 96
#define DD 192
#define KK 4
#define NN 16
#define RR 6
#define NCH 96
#define LC 24
#define COUT 192
#define OH 24
#define OW 24
#define OHW 576
#define NPX 1152
#define NTOT 4608
#define EPSF 1e-5f

typedef __attribute__((ext_vector_type(8))) short bf16x8;
typedef __attribute__((ext_vector_type(4))) float f32x4;

__device__ __forceinline__ short f2bf(float f) {
  unsigned u = __float_as_uint(f);
  unsigned r = (u + 0x7fffu + ((u >> 16) & 1u)) >> 16;
  return (short)r;
}

// ---------------- K1: prep: LN stats, WgT, At3 (fp32), bf16 conv weights -----
__global__ __launch_bounds__(256) void k_prep(const float* __restrict__ x,
                                              const float* __restrict__ g,
                                              const float* __restrict__ b,
                                              const float* __restrict__ inw,
                                              const float* __restrict__ xpw,
                                              const float* __restrict__ w31,
                                              const float* __restrict__ w32,
                                              const float* __restrict__ w33,
                                              const float* __restrict__ w1,
                                              const float* __restrict__ wout,
                                              float* __restrict__ stats,
                                              float* __restrict__ WgT,
                                              float* __restrict__ sWg,
                                              float* __restrict__ sWb,
                                              float* __restrict__ At3,
                                              short* __restrict__ At1b,
                                              short* __restrict__ At2b,
                                              short* __restrict__ woutb) {
  int bx = blockIdx.x;
  int tid = threadIdx.x;
  if (bx < 72) {
    int bb = bx / 36; int l0 = (bx % 36) * 64;
    int p = tid >> 2, q = tid & 3;
    int l = l0 + p;
    const float* xp = x + bb * CIN * LL + l;
    float s = 0.f, ss = 0.f;
    for (int c = q; c < CIN; c += 4) { float v = xp[c * LL]; s += v; ss += v * v; }
    s += __shfl_xor(s, 1, 64); s += __shfl_xor(s, 2, 64);
    ss += __shfl_xor(ss, 1, 64); ss += __shfl_xor(ss, 2, 64);
    if (q == 0) {
      float m = s / CIN; float var = ss / CIN - m * m;
      stats[(bb * LL + l) * 2 + 0] = m;
      stats[(bb * LL + l) * 2 + 1] = rsqrtf(var + EPSF);
    }
  } else if (bx == 72) {
    for (int e = tid; e < 2 * DD; e += 256) {
      float swg = 0.f, swb = 0.f;
      for (int c = 0; c < CIN; c++) {
        float w = inw[e * CIN + c];
        float wg = w * g[c];
        WgT[c * 384 + e] = wg;
        swg += wg; swb += w * b[c];
      }
      sWg[e] = swg; sWb[e] = swb;
    }
  } else if (bx < 217) {
    int idx = (bx - 73) * 256 + tid;
    if (idx < 192 * 192) {
      int m = idx % 192, d = idx / 192;
      At3[idx] = (m < 152) ? xpw[m * 192 + d] : 0.f;
    }
  } else if (bx < 2161) {
    int i = (bx - 217) * 256 + tid;
    if (i < 497664) {                     // At1b[m][k], 576 x 864
      float v;
      if (i < 165888) v = w31[i];
      else if (i < 331776) v = w32[i - 165888];
      else {
        int k = i % 864; int m = i / 864 - 384;
        v = (k % 9 == 4) ? w1[m * 96 + k / 9] : 0.f;
      }
      At1b[i] = f2bf(v);
    }
  } else if (bx < 3457) {
    int i = (bx - 2161) * 256 + tid;
    if (i < 331776) At2b[i] = f2bf(w33[i]);  // At2b[m][k], 192 x 1728
  } else {
    int i = (bx - 3457) * 256 + tid;
    if (i < 18432) woutb[i] = f2bf(wout[i]); // [e=96][d=192]
  }
}

// ---------------- K3: depthwise 3x3 + silu -> xs (2 layouts) + xsl -----------
__global__ __launch_bounds__(256) void k_dwconv(const float* __restrict__ xin,
                                                const float* __restrict__ wdw,
                                                const float* __restrict__ bdw,
                                                float* __restrict__ xs,
                                                float* __restrict__ xsl) {
  __shared__ float vt[32 * 50];
  int bid = blockIdx.x;
  int bb = bid / 288; int r = bid % 288; int dg = r / 72; int tile = r % 72;
  int l0 = tile * 32;
  int d0 = dg * 48;
  for (int i = threadIdx.x; i < 32 * 48; i += 256) {
    int lj = i & 31, dl = i >> 5;
    int d = d0 + dl;
    int l = l0 + lj;
    int h = l / WW, w = l % WW;
    const float* xp = xin + (bb * DD + d) * LL;
    const float* wq = wdw + d * 9;
    float acc = bdw[d];
#pragma unroll
    for (int kh = 0; kh < 3; kh++) {
      int ih = h + kh - 1; if (ih < 0 || ih >= HH) continue;
#pragma unroll
      for (int kw = 0; kw < 3; kw++) {
        int iw = w + kw - 1; if (iw < 0 || iw >= WW) continue;
        acc += xp[ih * WW + iw] * wq[kh * 3 + kw];
      }
    }
    float v = acc / (1.f + __expf(-acc));
    vt[lj * 50 + dl] = v;
    xsl[(size_t)d * NTOT + bb * LL + l] = v;
  }
  __syncthreads();
  for (int j = threadIdx.x; j < 32 * 48; j += 256) {
    int lj = j / 48, dl = j - lj * 48;
    int d = d0 + dl;
    int l = l0 + lj;
    int h = l / WW, w = l % WW;
    int lt = w * HH + h;
    float v = vt[lj * 50 + dl];
    xs[((size_t)(bb * 2 + 0) * LL + l) * DD + d] = v;
    xs[((size_t)(bb * 2 + 1) * LL + lt) * DD + d] = v;
  }
}

// ---------------- K-dtsplit: C1 -> delta (softplus) + Bsb/Csb, permuted ------
__global__ __launch_bounds__(256) void k_dtsplit(const float* __restrict__ C1,
                                                 const float* __restrict__ dtw,
                                                 const float* __restrict__ dtb,
                                                 float* __restrict__ Bsb,
                                                 float* __restrict__ Csb,
                                                 float* __restrict__ delta) {
  __shared__ float lds[38 * 33];
  int bid = blockIdx.x;
  int tile = bid % 72; int bk = bid / 72; int bb = bk >> 2; int k = bk & 3;
  int l0 = tile * 32;
  int tid = threadIdx.x;
  for (int i = tid; i < 38 * 32; i += 256) {
    int r = i >> 5, lj = i & 31;
    lds[r * 33 + lj] = C1[(size_t)(k * 38 + r) * NTOT + bb * LL + l0 + lj];
  }
  __syncthreads();
  for (int i = tid; i < 32 * 16; i += 256) {
    int lj = i >> 4, n = i & 15;
    int l = l0 + lj; int h = l / WW, w = l % WW; int lt = w * HH + h;
    int pos = (k == 0) ? l : (k == 1) ? lt : (k == 2) ? (LL - 1 - l) : (LL - 1 - lt);
    size_t base = ((size_t)bk * LL + pos) * NN + n;
    Bsb[base] = lds[(6 + n) * 33 + lj];
    Csb[base] = lds[(22 + n) * 33 + lj];
  }
  for (int i = tid; i < 32 * 192; i += 256) {
    int lj = i / 192, d = i - lj * 192;
    int l = l0 + lj; int h = l / WW, w = l % WW; int lt = w * HH + h;
    int pos = (k == 0) ? l : (k == 1) ? lt : (k == 2) ? (LL - 1 - l) : (LL - 1 - lt);
    const float* wd = dtw + (k * DD + d) * RR;
    float acc = dtb[k * DD + d];
#pragma unroll
    for (int r = 0; r < RR; r++) acc += wd[r] * lds[r * 33 + lj];
    float sp = acc > 20.f ? acc : log1pf(__expf(acc));
    delta[((size_t)bk * LL + pos) * DD + d] = sp;
  }
}

// ---------------- K5a: scan pass 1 -------------------------------------------
__global__ __launch_bounds__(192) void k_scan1(const float* __restrict__ delta,
                                               const float* __restrict__ xs,
                                               const float* __restrict__ Bsb,
                                               const float* __restrict__ A_logs,
                                               float* __restrict__ Pbuf,
                                               float* __restrict__ Sbuf) {
  __shared__ float Bls[LC * NN];
  int bid = blockIdx.x;
  int c = bid % NCH; int bk = bid / NCH; int k = bk & 3; int bb = bk >> 2;
  int t0 = c * LC;
  int d = threadIdx.x;
  const float* bp = Bsb + ((size_t)bk * LL + t0) * NN;
  for (int i = d; i < LC * NN; i += 192) Bls[i] = bp[i];
  float A[NN];
  {
    const float4* ap = (const float4*)(A_logs + (k * DD + d) * NN);
#pragma unroll
    for (int j = 0; j < 4; j++) {
      float4 a4 = ap[j];
      A[4 * j + 0] = -__expf(a4.x); A[4 * j + 1] = -__expf(a4.y);
      A[4 * j + 2] = -__expf(a4.z); A[4 * j + 3] = -__expf(a4.w);
    }
  }
  bool seq = true;
#pragma unroll
  for (int n = 0; n < NN; n++) seq = seq && (fabsf(A[n] + (float)(n + 1)) < 1e-3f);
  float h[NN];
#pragma unroll
  for (int n = 0; n < NN; n++) h[n] = 0.f;
  float sd = 0.f;
  __syncthreads();
  const float* dp = delta + ((size_t)bk * LL + t0) * DD + d;
  const float* xpb = xs + ((size_t)(bb * 2 + (k & 1)) * LL) * DD + d;
  const float* xp; int xstep;
  if (k < 2) { xp = xpb + (size_t)t0 * DD; xstep = DD; }
  else       { xp = xpb + (size_t)(LL - 1 - t0) * DD; xstep = -DD; }
#pragma unroll 2
  for (int t = 0; t < LC; ++t) {
    float dt = dp[t * DD];
    float xv = xp[t * xstep];
    float u = dt * xv;
    sd += dt;
    float dA[NN];
    if (seq) {
      float q = __expf(-dt);
      float q2 = q * q, q4 = q2 * q2, q8 = q4 * q4;
      dA[0] = q; dA[1] = q2; dA[2] = q2 * q; dA[3] = q4;
      dA[4] = q4 * q; dA[5] = q4 * q2; dA[6] = q4 * dA[2]; dA[7] = q8;
      dA[8] = q8 * q; dA[9] = q8 * q2; dA[10] = q8 * dA[2]; dA[11] = q8 * q4;
      dA[12] = q8 * dA[4]; dA[13] = q8 * dA[5]; dA[14] = q8 * dA[6]; dA[15] = q8 * q8;
    } else {
#pragma unroll
      for (int n = 0; n < NN; n++) dA[n] = __expf(dt * A[n]);
    }
    const float4* b4 = (const float4*)&Bls[t * NN];
#pragma unroll
    for (int j = 0; j < 4; j++) {
      float4 bv = b4[j];
      h[4 * j + 0] = dA[4 * j + 0] * h[4 * j + 0] + u * bv.x;
      h[4 * j + 1] = dA[4 * j + 1] * h[4 * j + 1] + u * bv.y;
      h[4 * j + 2] = dA[4 * j + 2] * h[4 * j + 2] + u * bv.z;
      h[4 * j + 3] = dA[4 * j + 3] * h[4 * j + 3] + u * bv.w;
    }
  }
  int chn = (bk * DD + d) * NN;
  float* pp = Pbuf + (size_t)c * 24576 + chn;
  float* sp = Sbuf + (size_t)c * 24576 + chn;
#pragma unroll
  for (int n = 0; n < NN; n++) { pp[n] = __expf(A[n] * sd); sp[n] = h[n]; }
}

// ---------------- K5b: combine chunks ----------------------------------------
__global__ __launch_bounds__(256) void k_scan2(const float* __restrict__ Pbuf,
                                               const float* __restrict__ Sbuf,
                                               float* __restrict__ Hinit) {
  int idx = blockIdx.x * 256 + threadIdx.x;
  float h = 0.f;
#pragma unroll 4
  for (int c = 0; c < NCH; c++) {
    Hinit[(size_t)c * 24576 + idx] = h;
    h = Pbuf[(size_t)c * 24576 + idx] * h + Sbuf[(size_t)c * 24576 + idx];
  }
}

// ---------------- K5c: scan pass 3 -------------------------------------------
__global__ __launch_bounds__(192) void k_scan3(const float* __restrict__ delta,
                                               const float* __restrict__ xs,
                                               const float* __restrict__ Bsb,
                                               const float* __restrict__ Csb,
                                               const float* __restrict__ A_logs,
                                               const float* __restrict__ Ds,
                                               const float* __restrict__ Hinit,
                                               float* __restrict__ ys) {
  __shared__ float Bls[LC * NN];
  __shared__ float Cls[LC * NN];
  int bid = blockIdx.x;
  int c = bid % NCH; int bk = bid / NCH; int k = bk & 3; int bb = bk >> 2;
  int t0 = c * LC;
  int d = threadIdx.x;
  const float* bp = Bsb + ((size_t)bk * LL + t0) * NN;
  const float* cp = Csb + ((size_t)bk * LL + t0) * NN;
  for (int i = d; i < LC * NN; i += 192) { Bls[i] = bp[i]; Cls[i] = cp[i]; }
  float A[NN];
  {
    const float4* ap = (const float4*)(A_logs + (k * DD + d) * NN);
#pragma unroll
    for (int j = 0; j < 4; j++) {
      float4 a4 = ap[j];
      A[4 * j + 0] = -__expf(a4.x); A[4 * j + 1] = -__expf(a4.y);
      A[4 * j + 2] = -__expf(a4.z); A[4 * j + 3] = -__expf(a4.w);
    }
  }
  bool seq = true;
#pragma unroll
  for (int n = 0; n < NN; n++) seq = seq && (fabsf(A[n] + (float)(n + 1)) < 1e-3f);
  float Dv = Ds[k * DD + d];
  float h[NN];
  {
    const float4* hp = (const float4*)(Hinit + (size_t)c * 24576 + (bk * DD + d) * NN);
#pragma unroll
    for (int j = 0; j < 4; j++) {
      float4 h4 = hp[j];
      h[4 * j + 0] = h4.x; h[4 * j + 1] = h4.y;
      h[4 * j + 2] = h4.z; h[4 * j + 3] = h4.w;
    }
  }
  __syncthreads();
  const float* dp = delta + ((size_t)bk * LL + t0) * DD + d;
  const float* xpb = xs + ((size_t)(bb * 2 + (k & 1)) * LL) * DD + d;
  const float* xp; int xstep;
  if (k < 2) { xp = xpb + (size_t)t0 * DD; xstep = DD; }
  else       { xp = xpb + (size_t)(LL - 1 - t0) * DD; xstep = -DD; }
  float* yp = ys + ((size_t)bk * LL + t0) * DD + d;
#pragma unroll 2
  for (int t = 0; t < LC; ++t) {
    float dt = dp[t * DD];
    float xv = xp[t * xstep];
    float u = dt * xv;
    float y = 0.f;
    float dA[NN];
    if (seq) {
      float q = __expf(-dt);
      float q2 = q * q, q4 = q2 * q2, q8 = q4 * q4;
      dA[0] = q; dA[1] = q2; dA[2] = q2 * q; dA[3] = q4;
      dA[4] = q4 * q; dA[5] = q4 * q2; dA[6] = q4 * dA[2]; dA[7] = q8;
      dA[8] = q8 * q; dA[9] = q8 * q2; dA[10] = q8 * dA[2]; dA[11] = q8 * q4;
      dA[12] = q8 * dA[4]; dA[13] = q8 * dA[5]; dA[14] = q8 * dA[6]; dA[15] = q8 * q8;
    } else {
#pragma unroll
      for (int n = 0; n < NN; n++) dA[n] = __expf(dt * A[n]);
    }
    const float4* b4 = (const float4*)&Bls[t * NN];
    const float4* c4 = (const float4*)&Cls[t * NN];
#pragma unroll
    for (int j = 0; j < 4; j++) {
      float4 bv = b4[j];
      float4 cc = c4[j];
      h[4 * j + 0] = dA[4 * j + 0] * h[4 * j + 0] + u * bv.x;
      h[4 * j + 1] = dA[4 * j + 1] * h[4 * j + 1] + u * bv.y;
      h[4 * j + 2] = dA[4 * j + 2] * h[4 * j + 2] + u * bv.z;
      h[4 * j + 3] = dA[4 * j + 3] * h[4 * j + 3] + u * bv.w;
      y += h[4 * j + 0] * cc.x + h[4 * j + 1] * cc.y
         + h[4 * j + 2] * cc.z + h[4 * j + 3] * cc.w;
    }
    yp[t * DD] = y + Dv * xv;
  }
}

// -------- K6: gather + out_norm LN + silu(z) + out_proj + residual -> xm -----
__global__ __launch_bounds__(256) void k_combineF(const float* __restrict__ ys,
                                                  const float* __restrict__ z,
                                                  const float* __restrict__ ong,
                                                  const float* __restrict__ onb,
                                                  const short* __restrict__ Wbf,
                                                  const float* __restrict__ x,
                                                  float* __restrict__ xm) {
  __shared__ float yt[32 * 194];
  __shared__ unsigned Wlu[96 * 98];
  int bx = blockIdx.x; int bb = bx / 72; int l0 = (bx % 72) * 32;
  int tid = threadIdx.x;
  const unsigned* Wu = (const unsigned*)Wbf;
  for (int i = tid; i < 96 * 96; i += 256) {
    int e = i / 96, d2 = i - e * 96;
    Wlu[e * 98 + d2] = Wu[i];
  }
  for (int i = tid; i < 32 * DD; i += 256) {
    int p = i / DD, d = i - p * DD;
    int l = l0 + p; int h = l / WW, w = l - h * WW;
    int t1 = w * HH + h;
    float v = ys[(((size_t)bb * KK + 0) * LL + l) * DD + d]
            + ys[(((size_t)bb * KK + 1) * LL + t1) * DD + d]
            + ys[(((size_t)bb * KK + 2) * LL + (LL - 1 - l)) * DD + d]
            + ys[(((size_t)bb * KK + 3) * LL + (LL - 1 - t1)) * DD + d];
    yt[p * 194 + d] = v;
  }
  __syncthreads();
  int p = tid >> 3, q = tid & 7;
  int l = l0 + p;
  float s = 0.f, ss = 0.f;
  for (int d = q * 24; d < q * 24 + 24; d++) { float v = yt[p * 194 + d]; s += v; ss += v * v; }
  s += __shfl_xor(s, 1, 64); s += __shfl_xor(s, 2, 64); s += __shfl_xor(s, 4, 64);
  ss += __shfl_xor(ss, 1, 64); ss += __shfl_xor(ss, 2, 64); ss += __shfl_xor(ss, 4, 64);
  float m = s / DD, var = ss / DD - m * m;
  float rr = rsqrtf(var + EPSF);
  const float* zp = z + (size_t)(bb * LL + l) * DD;
  for (int d = q * 24; d < q * 24 + 24; d++) {
    float v = (yt[p * 194 + d] - m) * rr * ong[d] + onb[d];
    float zv = zp[d];
    yt[p * 194 + d] = v * zv / (1.f + __expf(-zv));
  }
  __syncthreads();
  float acc[12];
#pragma unroll
  for (int j = 0; j < 12; j++) acc[j] = 0.f;
  for (int d2 = 0; d2 < 96; d2++) {
    float2 y2 = *(float2*)&yt[p * 194 + 2 * d2];
#pragma unroll
    for (int j = 0; j < 12; j++) {
      unsigned wv = Wlu[(q * 12 + j) * 98 + d2];
      float wlo = __uint_as_float(wv << 16);
      float whi = __uint_as_float(wv & 0xffff0000u);
      acc[j] += y2.x * wlo + y2.y * whi;
    }
  }
#pragma unroll
  for (int j = 0; j < 12; j++) {
    int e = q * 12 + j;
    size_t off = ((size_t)bb * CIN + e) * LL + l;
    xm[off] = x[off] + acc[j];
  }
}

// ---------------- K10: plain fp32 tiled GEMM (x_proj) ------------------------
template<int MT, int KCHUNK, int NB>
__global__ __launch_bounds__(256) void k_gemm(const float* __restrict__ At,
                                              const float* __restrict__ Bm,
                                              float* __restrict__ Cout) {
  __shared__ float As[16][64];
  __shared__ float Bs[16][64];
  int n0 = blockIdx.x * 64;
  int m0 = blockIdx.y * 64;
  int kz = blockIdx.z;
  int k0 = kz * KCHUNK;
  int tid = threadIdx.x;
  int lr = tid >> 4;
  int lc = (tid & 15) * 4;
  int tm = tid >> 4;
  int tn = tid & 15;
  float acc[4][4] = {};
  for (int ks = 0; ks < KCHUNK; ks += 16) {
    int kg = k0 + ks + lr;
    *(float4*)&As[lr][lc] = *(const float4*)&At[kg * MT + m0 + lc];
    *(float4*)&Bs[lr][lc] = *(const float4*)&Bm[(size_t)kg * NB + n0 + lc];
    __syncthreads();
#pragma unroll
    for (int kk = 0; kk < 16; kk++) {
      float4 a = *(float4*)&As[kk][tm * 4];
      float4 b = *(float4*)&Bs[kk][tn * 4];
      acc[0][0] += a.x * b.x; acc[0][1] += a.x * b.y; acc[0][2] += a.x * b.z; acc[0][3] += a.x * b.w;
      acc[1][0] += a.y * b.x; acc[1][1] += a.y * b.y; acc[1][2] += a.y * b.z; acc[1][3] += a.y * b.w;
      acc[2][0] += a.z * b.x; acc[2][1] += a.z * b.y; acc[2][2] += a.z * b.z; acc[2][3] += a.z * b.w;
      acc[3][0] += a.w * b.x; acc[3][1] += a.w * b.y; acc[3][2] += a.w * b.z; acc[3][3] += a.w * b.w;
    }
    __syncthreads();
  }
  float* cp = Cout + ((size_t)kz * MT + m0) * NB + n0;
#pragma unroll
  for (int i = 0; i < 4; i++) {
    float4 v = {acc[i][0], acc[i][1], acc[i][2], acc[i][3]};
    *(float4*)&cp[(size_t)(tm * 4 + i) * NB + tn * 4] = v;
  }
}

// ---------------- K10m: bf16-MFMA conv GEMM with fused im2col, split-K -------
template<int MT, int KTOT, int KCHUNK, int CI, int IH, int STRIDE>
__global__ __launch_bounds__(256) void k_cgemm_mfma(const short* __restrict__ Abf,
                                                    const float* __restrict__ SRC,
                                                    float* __restrict__ Cout) {
  __shared__ short As[64][40];
  __shared__ short Bs[64][40];
  int n0 = blockIdx.x * 64;
  int m0 = blockIdx.y * 64;
  int kz = blockIdx.z;
  int k0 = kz * KCHUNK;
  int tid = threadIdx.x;
  int lane = tid & 63;
  int wv = tid >> 6;
  int row16 = lane & 15;
  int kg = lane >> 4;
  int sm = tid >> 2;
  int sk8 = (tid & 3) * 8;
  int n = n0 + sm;
  int bb = n / OHW; int rem = n - bb * OHW;
  int oh = rem / OW, ow = rem - oh * OW;
  f32x4 acc[4];
#pragma unroll
  for (int i = 0; i < 4; i++) acc[i] = (f32x4){0.f, 0.f, 0.f, 0.f};
  for (int ks = 0; ks < KCHUNK; ks += 32) {
    *(bf16x8*)&As[sm][sk8] =
        *(const bf16x8*)&Abf[(size_t)(m0 + sm) * KTOT + k0 + ks + sk8];
    bf16x8 bvv;
#pragma unroll
    for (int j = 0; j < 8; j++) {
      int k = k0 + ks + sk8 + j;
      int ci = k / 9; int r9 = k - ci * 9;
      int kh = r9 / 3, kw = r9 - kh * 3;
      int ih = STRIDE * oh + kh - 1;
      int iw = STRIDE * ow + kw - 1;
      float v = (ih >= 0 && ih < IH && iw >= 0 && iw < IH)
              ? SRC[((size_t)(bb * CI + ci) * IH + ih) * IH + iw] : 0.f;
      bvv[j] = f2bf(v);
    }
    *(bf16x8*)&Bs[sm][sk8] = bvv;
    __syncthreads();
    bf16x8 a = *(const bf16x8*)&As[wv * 16 + row16][kg * 8];
#pragma unroll
    for (int tn = 0; tn < 4; tn++) {
      bf16x8 b = *(const bf16x8*)&Bs[tn * 16 + row16][kg * 8];
      acc[tn] = __builtin_amdgcn_mfma_f32_16x16x32_bf16(a, b, acc[tn], 0, 0, 0);
    }
    __syncthreads();
  }
#pragma unroll
  for (int tn = 0; tn < 4; tn++) {
    int col = n0 + tn * 16 + row16;
    int rowb = m0 + wv * 16 + kg * 4;
#pragma unroll
    for (int i = 0; i < 4; i++)
      Cout[((size_t)kz * MT + rowb + i) * NPX + col] = acc[tn][i];
  }
}

// ---------------- K10F: per-batch fp32 GEMM, LN-folded in_proj epilogue ------
template<int MT, int KD>
__global__ __launch_bounds__(256) void k_gemmF(const float* __restrict__ At,
                                               const float* __restrict__ Bm,
                                               int ldb, int boffB,
                                               float* __restrict__ C0,
                                               int ldc, int boffC,
                                               const float* __restrict__ a0,
                                               const float* __restrict__ a1,
                                               const float* __restrict__ a2,
                                               float* __restrict__ a3) {
  __shared__ float As[16][64];
  __shared__ float Bs[16][64];
  int n0 = blockIdx.x * 64;
  int m0 = blockIdx.y * 64;
  int bb = blockIdx.z;
  const float* B = Bm + (size_t)bb * boffB;
  int tid = threadIdx.x;
  int lr = tid >> 4;
  int lc = (tid & 15) * 4;
  int tm = tid >> 4;
  int tn = tid & 15;
  float acc[4][4] = {};
  for (int ks = 0; ks < KD; ks += 16) {
    *(float4*)&As[lr][lc] = *(const float4*)&At[(ks + lr) * MT + m0 + lc];
    *(float4*)&Bs[lr][lc] = *(const float4*)&B[(size_t)(ks + lr) * ldb + n0 + lc];
    __syncthreads();
#pragma unroll
    for (int kk = 0; kk < 16; kk++) {
      float4 a = *(float4*)&As[kk][tm * 4];
      float4 b = *(float4*)&Bs[kk][tn * 4];
      acc[0][0] += a.x * b.x; acc[0][1] += a.x * b.y; acc[0][2] += a.x * b.z; acc[0][3] += a.x * b.w;
      acc[1][0] += a.y * b.x; acc[1][1] += a.y * b.y; acc[1][2] += a.y * b.z; acc[1][3] += a.y * b.w;
      acc[2][0] += a.z * b.x; acc[2][1] += a.z * b.y; acc[2][2] += a.z * b.z; acc[2][3] += a.z * b.w;
      acc[3][0] += a.w * b.x; acc[3][1] += a.w * b.y; acc[3][2] += a.w * b.z; acc[3][3] += a.w * b.w;
    }
    __syncthreads();
  }
  int n = n0 + tn * 4;
  float m_[4], r_[4];
#pragma unroll
  for (int j = 0; j < 4; j++) {
    m_[j] = a0[((size_t)bb * LL + n + j) * 2];
    r_[j] = a0[((size_t)bb * LL + n + j) * 2 + 1];
  }
#pragma unroll
  for (int i = 0; i < 4; i++) {
    int e = m0 + tm * 4 + i;
    float swg = a1[e], swb = a2[e];
    float v0 = r_[0] * (acc[i][0] - m_[0] * swg) + swb;
    float v1 = r_[1] * (acc[i][1] - m_[1] * swg) + swb;
    float v2 = r_[2] * (acc[i][2] - m_[2] * swg) + swb;
    float v3 = r_[3] * (acc[i][3] - m_[3] * swg) + swb;
    if (e < DD) {
      float4 v = {v0, v1, v2, v3};
      *(float4*)&C0[(size_t)bb * boffC + (size_t)e * ldc + n] = v;
    } else {
      a3[((size_t)bb * LL + n + 0) * DD + (e - DD)] = v0;
      a3[((size_t)bb * LL + n + 1) * DD + (e - DD)] = v1;
      a3[((size_t)bb * LL + n + 2) * DD + (e - DD)] = v2;
      a3[((size_t)bb * LL + n + 3) * DD + (e - DD)] = v3;
    }
  }
}

// ---------------- K11: reduce split-K (9): x2-BN / t3 / x1-BN ----------------
__global__ __launch_bounds__(256) void k_reduce1(const float* __restrict__ Cp1,
                                                 const float* __restrict__ b1,
                                                 const float* __restrict__ b31,
                                                 const float* __restrict__ b32,
                                                 const float* __restrict__ bn_g,
                                                 const float* __restrict__ bn_b,
                                                 const float* __restrict__ bn_m,
                                                 const float* __restrict__ bn_v,
                                                 const float* __restrict__ prelu_a,
                                                 float* __restrict__ out,
                                                 float* __restrict__ t3) {
  int idx = blockIdx.x * 256 + threadIdx.x;
  if (idx >= 576 * NPX) return;
  int m = idx / NPX, n = idx % NPX;
  float s = 0.f;
#pragma unroll
  for (int c = 0; c < 9; c++) s += Cp1[(size_t)c * 576 * NPX + idx];
  int bb = n / OHW, o = n % OHW;
  if (m < 192) {
    s += b31[m];
    int cc = 192 + m;
    float scale = rsqrtf(bn_v[cc] + EPSF) * bn_g[cc];
    float v = s * scale + (bn_b[cc] - bn_m[cc] * scale);
    float a = prelu_a[0];
    out[((size_t)bb * 576 + cc) * OHW + o] = v > 0.f ? v : a * v;
  } else if (m < 384) {
    s += b32[m - 192];
    t3[((size_t)bb * COUT + (m - 192)) * OHW + o] = s;
  } else {
    s += b1[m - 384];
    int cc = m - 384;
    float scale = rsqrtf(bn_v[cc] + EPSF) * bn_g[cc];
    float v = s * scale + (bn_b[cc] - bn_m[cc] * scale);
    float a = prelu_a[0];
    out[((size_t)bb * 576 + cc) * OHW + o] = v > 0.f ? v : a * v;
  }
}

// ---------------- K12: reduce split-K (9) w33 -> out x3 w/ BN ----------------
__global__ __launch_bounds__(256) void k_reduce2(const float* __restrict__ Cp2,
                                                 const float* __restrict__ b33,
                                                 const float* __restrict__ bn_g,
                                                 const float* __restrict__ bn_b,
                                                 const float* __restrict__ bn_m,
                                                 const float* __restrict__ bn_v,
                                                 const float* __restrict__ prelu_a,
                                                 float* __restrict__ out) {
  int idx = blockIdx.x * 256 + threadIdx.x;
  if (idx >= 192 * NPX) return;
  int m = idx / NPX, n = idx % NPX;
  float s = b33[m];
#pragma unroll
  for (int c = 0; c < 9; c++) s += Cp2[(size_t)c * 192 * NPX + idx];
  int bb = n / OHW, o = n % OHW;
  int cc = 384 + m;
  float scale = rsqrtf(bn_v[cc] + EPSF) * bn_g[cc];
  float v = s * scale + (bn_b[cc] - bn_m[cc] * scale);
  float a = prelu_a[0];
  out[((size_t)bb * 576 + cc) * OHW + o] = v > 0.f ? v : a * v;
}

extern "C" void kernel_launch(void* const* d_in, const int* in_sizes, int n_in,
                              void* d_out, int out_size, void* d_ws, size_t ws_size,
                              hipStream_t stream) {
  const float* x        = (const float*)d_in[0];
  const float* ln_g     = (const float*)d_in[1];
  const float* ln_b     = (const float*)d_in[2];
  const float* in_proj_w= (const float*)d_in[3];
  const float* dwconv_w = (const float*)d_in[4];
  const float* dwconv_b = (const float*)d_in[5];
  const float* x_proj_w = (const float*)d_in[6];
  const float* dt_w     = (const float*)d_in[7];
  const float* dt_b     = (const float*)d_in[8];
  const float* A_logs   = (const float*)d_in[9];
  const float* Ds       = (const float*)d_in[10];
  const float* out_norm_g = (const float*)d_in[11];
  const float* out_norm_b = (const float*)d_in[12];
  const float* out_proj_w = (const float*)d_in[13];
  const float* w1  = (const float*)d_in[14];
  const float* b1  = (const float*)d_in[15];
  const float* w31 = (const float*)d_in[16];
  const float* b31 = (const float*)d_in[17];
  const float* w32 = (const float*)d_in[18];
  const float* b32 = (const float*)d_in[19];
  const float* w33 = (const float*)d_in[20];
  const float* b33 = (const float*)d_in[21];
  const float* bn_g = (const float*)d_in[22];
  const float* bn_b = (const float*)d_in[23];
  const float* bn_m = (const float*)d_in[24];
  const float* bn_v = (const float*)d_in[25];
  const float* prelu_a = (const float*)d_in[26];

  float* ws = (float*)d_ws;
  float* stats = ws + 0;           //   9216
  float* WgT   = ws + 16384;       //  36864
  float* sWg   = ws + 65536;       //    384
  float* sWb   = ws + 66048;       //    384
  float* At3   = ws + 98304;       //  36864
  short* At1b  = (short*)(ws + 147456);   // 497664 shorts
  short* At2b  = (short*)(ws + 397312);   // 331776 shorts
  short* woutb = (short*)(ws + 565248);   //  18432 shorts
  float* xin   = ws + 2097152;     // 884736
  float* z     = ws + 3145728;     // 884736
  float* xs    = ws + 4194304;     // 1769472
  float* xsl   = ws + 8388608;     // 884736
  float* C1    = ws + 9437184;     // 884736
  float* delta = ws + 10485760;    // 3538944
  float* Bsb   = ws + 14155776;    // 294912
  float* Csb   = ws + 14680064;    // 294912
  float* Pbuf  = ws + 15728640;    // 2359296
  float* Sbuf  = ws + 18874368;    // 2359296
  float* Hinit = ws + 22020096;    // 2359296
  float* ys    = ws + 25165824;    // 3538944
  float* xm    = ws + 29360128;    // 442368
  float* t3    = ws + 30408704;    // 221184
  float* Cp1   = ws + 31457280;    // 5971968 (9 x 576 x 1152)
  float* Cp2   = ws + 37748736;    // 1990656 (9 x 192 x 1152)
  float* out = (float*)d_out;

  k_prep<<<3529, 256, 0, stream>>>(x, ln_g, ln_b, in_proj_w, x_proj_w,
                                   w31, w32, w33, w1, out_proj_w,
                                   stats, WgT, sWg, sWb, At3, At1b, At2b, woutb);
  k_gemmF<384, 96><<<dim3(36, 6, 2), 256, 0, stream>>>(
      WgT, x, LL, CIN * LL, xin, LL, DD * LL, stats, sWg, sWb, z);
  k_dwconv<<<576, 256, 0, stream>>>(xin, dwconv_w, dwconv_b, xs, xsl);
  k_gemm<192, 192, NTOT><<<dim3(72, 3, 1), 256, 0, stream>>>(At3, xsl, C1);
  k_dtsplit<<<576, 256, 0, stream>>>(C1, dt_w, dt_b, Bsb, Csb, delta);
  k_scan1<<<768, 192, 0, stream>>>(delta, xs, Bsb, A_logs, Pbuf, Sbuf);
  k_scan2<<<96, 256, 0, stream>>>(Pbuf, Sbuf, Hinit);
  k_scan3<<<768, 192, 0, stream>>>(delta, xs, Bsb, Csb, A_logs, Ds, Hinit, ys);
  k_combineF<<<144, 256, 0, stream>>>(ys, z, out_norm_g, out_norm_b, woutb, x, xm);
  // conv1+2 (+1x1): M=576, K=864, split-K 9, bf16 MFMA
  k_cgemm_mfma<576, 864, 96, CIN, HH, 2><<<dim3(18, 9, 9), 256, 0, stream>>>(
      At1b, xm, Cp1);
  k_reduce1<<<2592, 256, 0, stream>>>(Cp1, b1, b31, b32, bn_g, bn_b, bn_m, bn_v,
                                      prelu_a, out, t3);
  // conv3b: M=192, K=1728, split-K 9, bf16 MFMA
  k_cgemm_mfma<192, 1728, 192, COUT, OH, 1><<<dim3(18, 3, 9), 256, 0, stream>>>(
      At2b, t3, Cp2);
  k_reduce2<<<864, 256, 0, stream>>>(Cp2, b33, bn_g, bn_b, bn_m, bn_v, prelu_a, out);
}

// Round 16
// 186.524 us; speedup vs baseline: 1.3870x; 1.0221x over previous
//
#include <hip/hip_runtime.h>
#include <math.h>

#define BB_ 2
#define HH 48
#define WW 48
#define LL 2304
#define CIN 96
#define DD 192
#define KK 4
#define NN 16
#define RR 6
#define NCH 96
#define LC 24
#define COUT 192
#define OH 24
#define OW 24
#define OHW 576
#define NPX 1152
#define NTOT 4608
#define EPSF 1e-5f

typedef __attribute__((ext_vector_type(8))) short bf16x8;
typedef __attribute__((ext_vector_type(4))) float f32x4;

__device__ __forceinline__ short f2bf(float f) {
  unsigned u = __float_as_uint(f);
  unsigned r = (u + 0x7fffu + ((u >> 16) & 1u)) >> 16;
  return (short)r;
}

// ---------------- K1: prep: LN stats, WgT, At3 (fp32), bf16 conv weights -----
__global__ __launch_bounds__(256) void k_prep(const float* __restrict__ x,
                                              const float* __restrict__ g,
                                              const float* __restrict__ b,
                                              const float* __restrict__ inw,
                                              const float* __restrict__ xpw,
                                              const float* __restrict__ w31,
                                              const float* __restrict__ w32,
                                              const float* __restrict__ w33,
                                              const float* __restrict__ w1,
                                              const float* __restrict__ wout,
                                              float* __restrict__ stats,
                                              float* __restrict__ WgT,
                                              float* __restrict__ sWg,
                                              float* __restrict__ sWb,
                                              float* __restrict__ At3,
                                              short* __restrict__ At1b,
                                              short* __restrict__ At2b,
                                              short* __restrict__ woutb) {
  int bx = blockIdx.x;
  int tid = threadIdx.x;
  if (bx < 72) {
    int bb = bx / 36; int l0 = (bx % 36) * 64;
    int p = tid >> 2, q = tid & 3;
    int l = l0 + p;
    const float* xp = x + bb * CIN * LL + l;
    float s = 0.f, ss = 0.f;
    for (int c = q; c < CIN; c += 4) { float v = xp[c * LL]; s += v; ss += v * v; }
    s += __shfl_xor(s, 1, 64); s += __shfl_xor(s, 2, 64);
    ss += __shfl_xor(ss, 1, 64); ss += __shfl_xor(ss, 2, 64);
    if (q == 0) {
      float m = s / CIN; float var = ss / CIN - m * m;
      stats[(bb * LL + l) * 2 + 0] = m;
      stats[(bb * LL + l) * 2 + 1] = rsqrtf(var + EPSF);
    }
  } else if (bx == 72) {
    for (int e = tid; e < 2 * DD; e += 256) {
      float swg = 0.f, swb = 0.f;
      for (int c = 0; c < CIN; c++) {
        float w = inw[e * CIN + c];
        float wg = w * g[c];
        WgT[c * 384 + e] = wg;
        swg += wg; swb += w * b[c];
      }
      sWg[e] = swg; sWb[e] = swb;
    }
  } else if (bx < 217) {
    int idx = (bx - 73) * 256 + tid;
    if (idx < 192 * 192) {
      int m = idx % 192, d = idx / 192;
      At3[idx] = (m < 152) ? xpw[m * 192 + d] : 0.f;
    }
  } else if (bx < 2161) {
    int i = (bx - 217) * 256 + tid;
    if (i < 497664) {                     // At1b[m][k], 576 x 864
      float v;
      if (i < 165888) v = w31[i];
      else if (i < 331776) v = w32[i - 165888];
      else {
        int k = i % 864; int m = i / 864 - 384;
        v = (k % 9 == 4) ? w1[m * 96 + k / 9] : 0.f;
      }
      At1b[i] = f2bf(v);
    }
  } else if (bx < 3457) {
    int i = (bx - 2161) * 256 + tid;
    if (i < 331776) At2b[i] = f2bf(w33[i]);  // At2b[m][k], 192 x 1728
  } else {
    int i = (bx - 3457) * 256 + tid;
    if (i < 18432) woutb[i] = f2bf(wout[i]); // [e=96][d=192]
  }
}

// ---------------- K3: depthwise 3x3 + silu -> xs (2 layouts) + xsl -----------
__global__ __launch_bounds__(256) void k_dwconv(const float* __restrict__ xin,
                                                const float* __restrict__ wdw,
                                                const float* __restrict__ bdw,
                                                float* __restrict__ xs,
                                                float* __restrict__ xsl) {
  __shared__ float vt[32 * 50];
  int bid = blockIdx.x;
  int bb = bid / 288; int r = bid % 288; int dg = r / 72; int tile = r % 72;
  int l0 = tile * 32;
  int d0 = dg * 48;
  for (int i = threadIdx.x; i < 32 * 48; i += 256) {
    int lj = i & 31, dl = i >> 5;
    int d = d0 + dl;
    int l = l0 + lj;
    int h = l / WW, w = l % WW;
    const float* xp = xin + (bb * DD + d) * LL;
    const float* wq = wdw + d * 9;
    float acc = bdw[d];
#pragma unroll
    for (int kh = 0; kh < 3; kh++) {
      int ih = h + kh - 1; if (ih < 0 || ih >= HH) continue;
#pragma unroll
      for (int kw = 0; kw < 3; kw++) {
        int iw = w + kw - 1; if (iw < 0 || iw >= WW) continue;
        acc += xp[ih * WW + iw] * wq[kh * 3 + kw];
      }
    }
    float v = acc / (1.f + __expf(-acc));
    vt[lj * 50 + dl] = v;
    xsl[(size_t)d * NTOT + bb * LL + l] = v;
  }
  __syncthreads();
  for (int j = threadIdx.x; j < 32 * 48; j += 256) {
    int lj = j / 48, dl = j - lj * 48;
    int d = d0 + dl;
    int l = l0 + lj;
    int h = l / WW, w = l % WW;
    int lt = w * HH + h;
    float v = vt[lj * 50 + dl];
    xs[((size_t)(bb * 2 + 0) * LL + l) * DD + d] = v;
    xs[((size_t)(bb * 2 + 1) * LL + lt) * DD + d] = v;
  }
}

// ---------------- K-dtsplit: C1 -> delta (softplus) + Bsb/Csb, permuted ------
__global__ __launch_bounds__(256) void k_dtsplit(const float* __restrict__ C1,
                                                 const float* __restrict__ dtw,
                                                 const float* __restrict__ dtb,
                                                 float* __restrict__ Bsb,
                                                 float* __restrict__ Csb,
                                                 float* __restrict__ delta) {
  __shared__ float lds[38 * 33];
  int bid = blockIdx.x;
  int tile = bid % 72; int bk = bid / 72; int bb = bk >> 2; int k = bk & 3;
  int l0 = tile * 32;
  int tid = threadIdx.x;
  for (int i = tid; i < 38 * 32; i += 256) {
    int r = i >> 5, lj = i & 31;
    lds[r * 33 + lj] = C1[(size_t)(k * 38 + r) * NTOT + bb * LL + l0 + lj];
  }
  __syncthreads();
  for (int i = tid; i < 32 * 16; i += 256) {
    int lj = i >> 4, n = i & 15;
    int l = l0 + lj; int h = l / WW, w = l % WW; int lt = w * HH + h;
    int pos = (k == 0) ? l : (k == 1) ? lt : (k == 2) ? (LL - 1 - l) : (LL - 1 - lt);
    size_t base = ((size_t)bk * LL + pos) * NN + n;
    Bsb[base] = lds[(6 + n) * 33 + lj];
    Csb[base] = lds[(22 + n) * 33 + lj];
  }
  for (int i = tid; i < 32 * 192; i += 256) {
    int lj = i / 192, d = i - lj * 192;
    int l = l0 + lj; int h = l / WW, w = l % WW; int lt = w * HH + h;
    int pos = (k == 0) ? l : (k == 1) ? lt : (k == 2) ? (LL - 1 - l) : (LL - 1 - lt);
    const float* wd = dtw + (k * DD + d) * RR;
    float acc = dtb[k * DD + d];
#pragma unroll
    for (int r = 0; r < RR; r++) acc += wd[r] * lds[r * 33 + lj];
    float sp = acc > 20.f ? acc : log1pf(__expf(acc));
    delta[((size_t)bk * LL + pos) * DD + d] = sp;
  }
}

// ---------------- K5a: scan pass 1 -------------------------------------------
__global__ __launch_bounds__(192) void k_scan1(const float* __restrict__ delta,
                                               const float* __restrict__ xs,
                                               const float* __restrict__ Bsb,
                                               const float* __restrict__ A_logs,
                                               float* __restrict__ Pbuf,
                                               float* __restrict__ Sbuf) {
  __shared__ float Bls[LC * NN];
  int bid = blockIdx.x;
  int c = bid % NCH; int bk = bid / NCH; int k = bk & 3; int bb = bk >> 2;
  int t0 = c * LC;
  int d = threadIdx.x;
  const float* bp = Bsb + ((size_t)bk * LL + t0) * NN;
  for (int i = d; i < LC * NN; i += 192) Bls[i] = bp[i];
  float A[NN];
  {
    const float4* ap = (const float4*)(A_logs + (k * DD + d) * NN);
#pragma unroll
    for (int j = 0; j < 4; j++) {
      float4 a4 = ap[j];
      A[4 * j + 0] = -__expf(a4.x); A[4 * j + 1] = -__expf(a4.y);
      A[4 * j + 2] = -__expf(a4.z); A[4 * j + 3] = -__expf(a4.w);
    }
  }
  bool seq = true;
#pragma unroll
  for (int n = 0; n < NN; n++) seq = seq && (fabsf(A[n] + (float)(n + 1)) < 1e-3f);
  float h[NN];
#pragma unroll
  for (int n = 0; n < NN; n++) h[n] = 0.f;
  float sd = 0.f;
  __syncthreads();
  const float* dp = delta + ((size_t)bk * LL + t0) * DD + d;
  const float* xpb = xs + ((size_t)(bb * 2 + (k & 1)) * LL) * DD + d;
  const float* xp; int xstep;
  if (k < 2) { xp = xpb + (size_t)t0 * DD; xstep = DD; }
  else       { xp = xpb + (size_t)(LL - 1 - t0) * DD; xstep = -DD; }
#pragma unroll 2
  for (int t = 0; t < LC; ++t) {
    float dt = dp[t * DD];
    float xv = xp[t * xstep];
    float u = dt * xv;
    sd += dt;
    float dA[NN];
    if (seq) {
      float q = __expf(-dt);
      float q2 = q * q, q4 = q2 * q2, q8 = q4 * q4;
      dA[0] = q; dA[1] = q2; dA[2] = q2 * q; dA[3] = q4;
      dA[4] = q4 * q; dA[5] = q4 * q2; dA[6] = q4 * dA[2]; dA[7] = q8;
      dA[8] = q8 * q; dA[9] = q8 * q2; dA[10] = q8 * dA[2]; dA[11] = q8 * q4;
      dA[12] = q8 * dA[4]; dA[13] = q8 * dA[5]; dA[14] = q8 * dA[6]; dA[15] = q8 * q8;
    } else {
#pragma unroll
      for (int n = 0; n < NN; n++) dA[n] = __expf(dt * A[n]);
    }
    const float4* b4 = (const float4*)&Bls[t * NN];
#pragma unroll
    for (int j = 0; j < 4; j++) {
      float4 bv = b4[j];
      h[4 * j + 0] = dA[4 * j + 0] * h[4 * j + 0] + u * bv.x;
      h[4 * j + 1] = dA[4 * j + 1] * h[4 * j + 1] + u * bv.y;
      h[4 * j + 2] = dA[4 * j + 2] * h[4 * j + 2] + u * bv.z;
      h[4 * j + 3] = dA[4 * j + 3] * h[4 * j + 3] + u * bv.w;
    }
  }
  int chn = (bk * DD + d) * NN;
  float* pp = Pbuf + (size_t)c * 24576 + chn;
  float* sp = Sbuf + (size_t)c * 24576 + chn;
#pragma unroll
  for (int n = 0; n < NN; n++) { pp[n] = __expf(A[n] * sd); sp[n] = h[n]; }
}

// ---------------- K5b: combine chunks ----------------------------------------
__global__ __launch_bounds__(256) void k_scan2(const float* __restrict__ Pbuf,
                                               const float* __restrict__ Sbuf,
                                               float* __restrict__ Hinit) {
  int idx = blockIdx.x * 256 + threadIdx.x;
  float h = 0.f;
  for (int c = 0; c < NCH; c++) {
    Hinit[(size_t)c * 24576 + idx] = h;
    h = Pbuf[(size_t)c * 24576 + idx] * h + Sbuf[(size_t)c * 24576 + idx];
  }
}

// ---------------- K5c: scan pass 3 -------------------------------------------
__global__ __launch_bounds__(192) void k_scan3(const float* __restrict__ delta,
                                               const float* __restrict__ xs,
                                               const float* __restrict__ Bsb,
                                               const float* __restrict__ Csb,
                                               const float* __restrict__ A_logs,
                                               const float* __restrict__ Ds,
                                               const float* __restrict__ Hinit,
                                               float* __restrict__ ys) {
  __shared__ float Bls[LC * NN];
  __shared__ float Cls[LC * NN];
  int bid = blockIdx.x;
  int c = bid % NCH; int bk = bid / NCH; int k = bk & 3; int bb = bk >> 2;
  int t0 = c * LC;
  int d = threadIdx.x;
  const float* bp = Bsb + ((size_t)bk * LL + t0) * NN;
  const float* cp = Csb + ((size_t)bk * LL + t0) * NN;
  for (int i = d; i < LC * NN; i += 192) { Bls[i] = bp[i]; Cls[i] = cp[i]; }
  float A[NN];
  {
    const float4* ap = (const float4*)(A_logs + (k * DD + d) * NN);
#pragma unroll
    for (int j = 0; j < 4; j++) {
      float4 a4 = ap[j];
      A[4 * j + 0] = -__expf(a4.x); A[4 * j + 1] = -__expf(a4.y);
      A[4 * j + 2] = -__expf(a4.z); A[4 * j + 3] = -__expf(a4.w);
    }
  }
  bool seq = true;
#pragma unroll
  for (int n = 0; n < NN; n++) seq = seq && (fabsf(A[n] + (float)(n + 1)) < 1e-3f);
  float Dv = Ds[k * DD + d];
  float h[NN];
  {
    const float4* hp = (const float4*)(Hinit + (size_t)c * 24576 + (bk * DD + d) * NN);
#pragma unroll
    for (int j = 0; j < 4; j++) {
      float4 h4 = hp[j];
      h[4 * j + 0] = h4.x; h[4 * j + 1] = h4.y;
      h[4 * j + 2] = h4.z; h[4 * j + 3] = h4.w;
    }
  }
  __syncthreads();
  const float* dp = delta + ((size_t)bk * LL + t0) * DD + d;
  const float* xpb = xs + ((size_t)(bb * 2 + (k & 1)) * LL) * DD + d;
  const float* xp; int xstep;
  if (k < 2) { xp = xpb + (size_t)t0 * DD; xstep = DD; }
  else       { xp = xpb + (size_t)(LL - 1 - t0) * DD; xstep = -DD; }
  float* yp = ys + ((size_t)bk * LL + t0) * DD + d;
#pragma unroll 2
  for (int t = 0; t < LC; ++t) {
    float dt = dp[t * DD];
    float xv = xp[t * xstep];
    float u = dt * xv;
    float y = 0.f;
    float dA[NN];
    if (seq) {
      float q = __expf(-dt);
      float q2 = q * q, q4 = q2 * q2, q8 = q4 * q4;
      dA[0] = q; dA[1] = q2; dA[2] = q2 * q; dA[3] = q4;
      dA[4] = q4 * q; dA[5] = q4 * q2; dA[6] = q4 * dA[2]; dA[7] = q8;
      dA[8] = q8 * q; dA[9] = q8 * q2; dA[10] = q8 * dA[2]; dA[11] = q8 * q4;
      dA[12] = q8 * dA[4]; dA[13] = q8 * dA[5]; dA[14] = q8 * dA[6]; dA[15] = q8 * q8;
    } else {
#pragma unroll
      for (int n = 0; n < NN; n++) dA[n] = __expf(dt * A[n]);
    }
    const float4* b4 = (const float4*)&Bls[t * NN];
    const float4* c4 = (const float4*)&Cls[t * NN];
#pragma unroll
    for (int j = 0; j < 4; j++) {
      float4 bv = b4[j];
      float4 cc = c4[j];
      h[4 * j + 0] = dA[4 * j + 0] * h[4 * j + 0] + u * bv.x;
      h[4 * j + 1] = dA[4 * j + 1] * h[4 * j + 1] + u * bv.y;
      h[4 * j + 2] = dA[4 * j + 2] * h[4 * j + 2] + u * bv.z;
      h[4 * j + 3] = dA[4 * j + 3] * h[4 * j + 3] + u * bv.w;
      y += h[4 * j + 0] * cc.x + h[4 * j + 1] * cc.y
         + h[4 * j + 2] * cc.z + h[4 * j + 3] * cc.w;
    }
    yp[t * DD] = y + Dv * xv;
  }
}

// -------- K6: gather + out_norm LN + silu(z) + out_proj + residual -> xm -----
__global__ __launch_bounds__(256) void k_combineF(const float* __restrict__ ys,
                                                  const float* __restrict__ z,
                                                  const float* __restrict__ ong,
                                                  const float* __restrict__ onb,
                                                  const short* __restrict__ Wbf,
                                                  const float* __restrict__ x,
                                                  float* __restrict__ xm) {
  __shared__ float yt[32 * 194];
  __shared__ unsigned Wlu[96 * 98];
  int bx = blockIdx.x; int bb = bx / 72; int l0 = (bx % 72) * 32;
  int tid = threadIdx.x;
  const unsigned* Wu = (const unsigned*)Wbf;
  for (int i = tid; i < 96 * 96; i += 256) {
    int e = i / 96, d2 = i - e * 96;
    Wlu[e * 98 + d2] = Wu[i];
  }
  for (int i = tid; i < 32 * DD; i += 256) {
    int p = i / DD, d = i - p * DD;
    int l = l0 + p; int h = l / WW, w = l - h * WW;
    int t1 = w * HH + h;
    float v = ys[(((size_t)bb * KK + 0) * LL + l) * DD + d]
            + ys[(((size_t)bb * KK + 1) * LL + t1) * DD + d]
            + ys[(((size_t)bb * KK + 2) * LL + (LL - 1 - l)) * DD + d]
            + ys[(((size_t)bb * KK + 3) * LL + (LL - 1 - t1)) * DD + d];
    yt[p * 194 + d] = v;
  }
  __syncthreads();
  int p = tid >> 3, q = tid & 7;
  int l = l0 + p;
  float s = 0.f, ss = 0.f;
  for (int d = q * 24; d < q * 24 + 24; d++) { float v = yt[p * 194 + d]; s += v; ss += v * v; }
  s += __shfl_xor(s, 1, 64); s += __shfl_xor(s, 2, 64); s += __shfl_xor(s, 4, 64);
  ss += __shfl_xor(ss, 1, 64); ss += __shfl_xor(ss, 2, 64); ss += __shfl_xor(ss, 4, 64);
  float m = s / DD, var = ss / DD - m * m;
  float rr = rsqrtf(var + EPSF);
  const float* zp = z + (size_t)(bb * LL + l) * DD;
  for (int d = q * 24; d < q * 24 + 24; d++) {
    float v = (yt[p * 194 + d] - m) * rr * ong[d] + onb[d];
    float zv = zp[d];
    yt[p * 194 + d] = v * zv / (1.f + __expf(-zv));
  }
  __syncthreads();
  float acc[12];
#pragma unroll
  for (int j = 0; j < 12; j++) acc[j] = 0.f;
  for (int d2 = 0; d2 < 96; d2++) {
    float2 y2 = *(float2*)&yt[p * 194 + 2 * d2];
#pragma unroll
    for (int j = 0; j < 12; j++) {
      unsigned wv = Wlu[(q * 12 + j) * 98 + d2];
      float wlo = __uint_as_float(wv << 16);
      float whi = __uint_as_float(wv & 0xffff0000u);
      acc[j] += y2.x * wlo + y2.y * whi;
    }
  }
#pragma unroll
  for (int j = 0; j < 12; j++) {
    int e = q * 12 + j;
    size_t off = ((size_t)bb * CIN + e) * LL + l;
    xm[off] = x[off] + acc[j];
  }
}

// ---------------- K10: plain fp32 tiled GEMM (x_proj) ------------------------
template<int MT, int KCHUNK, int NB>
__global__ __launch_bounds__(256) void k_gemm(const float* __restrict__ At,
                                              const float* __restrict__ Bm,
                                              float* __restrict__ Cout) {
  __shared__ float As[16][64];
  __shared__ float Bs[16][64];
  int n0 = blockIdx.x * 64;
  int m0 = blockIdx.y * 64;
  int kz = blockIdx.z;
  int k0 = kz * KCHUNK;
  int tid = threadIdx.x;
  int lr = tid >> 4;
  int lc = (tid & 15) * 4;
  int tm = tid >> 4;
  int tn = tid & 15;
  float acc[4][4] = {};
  for (int ks = 0; ks < KCHUNK; ks += 16) {
    int kg = k0 + ks + lr;
    *(float4*)&As[lr][lc] = *(const float4*)&At[kg * MT + m0 + lc];
    *(float4*)&Bs[lr][lc] = *(const float4*)&Bm[(size_t)kg * NB + n0 + lc];
    __syncthreads();
#pragma unroll
    for (int kk = 0; kk < 16; kk++) {
      float4 a = *(float4*)&As[kk][tm * 4];
      float4 b = *(float4*)&Bs[kk][tn * 4];
      acc[0][0] += a.x * b.x; acc[0][1] += a.x * b.y; acc[0][2] += a.x * b.z; acc[0][3] += a.x * b.w;
      acc[1][0] += a.y * b.x; acc[1][1] += a.y * b.y; acc[1][2] += a.y * b.z; acc[1][3] += a.y * b.w;
      acc[2][0] += a.z * b.x; acc[2][1] += a.z * b.y; acc[2][2] += a.z * b.z; acc[2][3] += a.z * b.w;
      acc[3][0] += a.w * b.x; acc[3][1] += a.w * b.y; acc[3][2] += a.w * b.z; acc[3][3] += a.w * b.w;
    }
    __syncthreads();
  }
  float* cp = Cout + ((size_t)kz * MT + m0) * NB + n0;
#pragma unroll
  for (int i = 0; i < 4; i++) {
    float4 v = {acc[i][0], acc[i][1], acc[i][2], acc[i][3]};
    *(float4*)&cp[(size_t)(tm * 4 + i) * NB + tn * 4] = v;
  }
}

// ---------------- K10m: bf16-MFMA conv GEMM with fused im2col, split-K -------
template<int MT, int KTOT, int KCHUNK, int CI, int IH, int STRIDE>
__global__ __launch_bounds__(256) void k_cgemm_mfma(const short* __restrict__ Abf,
                                                    const float* __restrict__ SRC,
                                                    float* __restrict__ Cout) {
  __shared__ short As[64][40];
  __shared__ short Bs[64][40];
  int n0 = blockIdx.x * 64;
  int m0 = blockIdx.y * 64;
  int kz = blockIdx.z;
  int k0 = kz * KCHUNK;
  int tid = threadIdx.x;
  int lane = tid & 63;
  int wv = tid >> 6;
  int row16 = lane & 15;
  int kg = lane >> 4;
  int sm = tid >> 2;
  int sk8 = (tid & 3) * 8;
  int n = n0 + sm;
  int bb = n / OHW; int rem = n - bb * OHW;
  int oh = rem / OW, ow = rem - oh * OW;
  f32x4 acc[4];
#pragma unroll
  for (int i = 0; i < 4; i++) acc[i] = (f32x4){0.f, 0.f, 0.f, 0.f};
  for (int ks = 0; ks < KCHUNK; ks += 32) {
    *(bf16x8*)&As[sm][sk8] =
        *(const bf16x8*)&Abf[(size_t)(m0 + sm) * KTOT + k0 + ks + sk8];
    bf16x8 bvv;
#pragma unroll
    for (int j = 0; j < 8; j++) {
      int k = k0 + ks + sk8 + j;
      int ci = k / 9; int r9 = k - ci * 9;
      int kh = r9 / 3, kw = r9 - kh * 3;
      int ih = STRIDE * oh + kh - 1;
      int iw = STRIDE * ow + kw - 1;
      float v = (ih >= 0 && ih < IH && iw >= 0 && iw < IH)
              ? SRC[((size_t)(bb * CI + ci) * IH + ih) * IH + iw] : 0.f;
      bvv[j] = f2bf(v);
    }
    *(bf16x8*)&Bs[sm][sk8] = bvv;
    __syncthreads();
    bf16x8 a = *(const bf16x8*)&As[wv * 16 + row16][kg * 8];
#pragma unroll
    for (int tn = 0; tn < 4; tn++) {
      bf16x8 b = *(const bf16x8*)&Bs[tn * 16 + row16][kg * 8];
      acc[tn] = __builtin_amdgcn_mfma_f32_16x16x32_bf16(a, b, acc[tn], 0, 0, 0);
    }
    __syncthreads();
  }
#pragma unroll
  for (int tn = 0; tn < 4; tn++) {
    int col = n0 + tn * 16 + row16;
    int rowb = m0 + wv * 16 + kg * 4;
#pragma unroll
    for (int i = 0; i < 4; i++)
      Cout[((size_t)kz * MT + rowb + i) * NPX + col] = acc[tn][i];
  }
}

// ---------------- K10F: per-batch fp32 GEMM, LN-folded in_proj epilogue ------
template<int MT, int KD>
__global__ __launch_bounds__(256) void k_gemmF(const float* __restrict__ At,
                                               const float* __restrict__ Bm,
                                               int ldb, int boffB,
                                               float* __restrict__ C0,
                                               int ldc, int boffC,
                                               const float* __restrict__ a0,
                                               const float* __restrict__ a1,
                                               const float* __restrict__ a2,
                                               float* __restrict__ a3) {
  __shared__ float As[16][64];
  __shared__ float Bs[16][64];
  int n0 = blockIdx.x * 64;
  int m0 = blockIdx.y * 64;
  int bb = blockIdx.z;
  const float* B = Bm + (size_t)bb * boffB;
  int tid = threadIdx.x;
  int lr = tid >> 4;
  int lc = (tid & 15) * 4;
  int tm = tid >> 4;
  int tn = tid & 15;
  float acc[4][4] = {};
  for (int ks = 0; ks < KD; ks += 16) {
    *(float4*)&As[lr][lc] = *(const float4*)&At[(ks + lr) * MT + m0 + lc];
    *(float4*)&Bs[lr][lc] = *(const float4*)&B[(size_t)(ks + lr) * ldb + n0 + lc];
    __syncthreads();
#pragma unroll
    for (int kk = 0; kk < 16; kk++) {
      float4 a = *(float4*)&As[kk][tm * 4];
      float4 b = *(float4*)&Bs[kk][tn * 4];
      acc[0][0] += a.x * b.x; acc[0][1] += a.x * b.y; acc[0][2] += a.x * b.z; acc[0][3] += a.x * b.w;
      acc[1][0] += a.y * b.x; acc[1][1] += a.y * b.y; acc[1][2] += a.y * b.z; acc[1][3] += a.y * b.w;
      acc[2][0] += a.z * b.x; acc[2][1] += a.z * b.y; acc[2][2] += a.z * b.z; acc[2][3] += a.z * b.w;
      acc[3][0] += a.w * b.x; acc[3][1] += a.w * b.y; acc[3][2] += a.w * b.z; acc[3][3] += a.w * b.w;
    }
    __syncthreads();
  }
  int n = n0 + tn * 4;
  float m_[4], r_[4];
#pragma unroll
  for (int j = 0; j < 4; j++) {
    m_[j] = a0[((size_t)bb * LL + n + j) * 2];
    r_[j] = a0[((size_t)bb * LL + n + j) * 2 + 1];
  }
#pragma unroll
  for (int i = 0; i < 4; i++) {
    int e = m0 + tm * 4 + i;
    float swg = a1[e], swb = a2[e];
    float v0 = r_[0] * (acc[i][0] - m_[0] * swg) + swb;
    float v1 = r_[1] * (acc[i][1] - m_[1] * swg) + swb;
    float v2 = r_[2] * (acc[i][2] - m_[2] * swg) + swb;
    float v3 = r_[3] * (acc[i][3] - m_[3] * swg) + swb;
    if (e < DD) {
      float4 v = {v0, v1, v2, v3};
      *(float4*)&C0[(size_t)bb * boffC + (size_t)e * ldc + n] = v;
    } else {
      a3[((size_t)bb * LL + n + 0) * DD + (e - DD)] = v0;
      a3[((size_t)bb * LL + n + 1) * DD + (e - DD)] = v1;
      a3[((size_t)bb * LL + n + 2) * DD + (e - DD)] = v2;
      a3[((size_t)bb * LL + n + 3) * DD + (e - DD)] = v3;
    }
  }
}

// ---------------- K11: reduce split-K (9): x2-BN / t3 / x1-BN ----------------
__global__ __launch_bounds__(256) void k_reduce1(const float* __restrict__ Cp1,
                                                 const float* __restrict__ b1,
                                                 const float* __restrict__ b31,
                                                 const float* __restrict__ b32,
                                                 const float* __restrict__ bn_g,
                                                 const float* __restrict__ bn_b,
                                                 const float* __restrict__ bn_m,
                                                 const float* __restrict__ bn_v,
                                                 const float* __restrict__ prelu_a,
                                                 float* __restrict__ out,
                                                 float* __restrict__ t3) {
  int idx = blockIdx.x * 256 + threadIdx.x;
  if (idx >= 576 * NPX) return;
  int m = idx / NPX, n = idx % NPX;
  float s = 0.f;
#pragma unroll
  for (int c = 0; c < 9; c++) s += Cp1[(size_t)c * 576 * NPX + idx];
  int bb = n / OHW, o = n % OHW;
  if (m < 192) {
    s += b31[m];
    int cc = 192 + m;
    float scale = rsqrtf(bn_v[cc] + EPSF) * bn_g[cc];
    float v = s * scale + (bn_b[cc] - bn_m[cc] * scale);
    float a = prelu_a[0];
    out[((size_t)bb * 576 + cc) * OHW + o] = v > 0.f ? v : a * v;
  } else if (m < 384) {
    s += b32[m - 192];
    t3[((size_t)bb * COUT + (m - 192)) * OHW + o] = s;
  } else {
    s += b1[m - 384];
    int cc = m - 384;
    float scale = rsqrtf(bn_v[cc] + EPSF) * bn_g[cc];
    float v = s * scale + (bn_b[cc] - bn_m[cc] * scale);
    float a = prelu_a[0];
    out[((size_t)bb * 576 + cc) * OHW + o] = v > 0.f ? v : a * v;
  }
}

// ---------------- K12: reduce split-K (9) w33 -> out x3 w/ BN ----------------
__global__ __launch_bounds__(256) void k_reduce2(const float* __restrict__ Cp2,
                                                 const float* __restrict__ b33,
                                                 const float* __restrict__ bn_g,
                                                 const float* __restrict__ bn_b,
                                                 const float* __restrict__ bn_m,
                                                 const float* __restrict__ bn_v,
                                                 const float* __restrict__ prelu_a,
                                                 float* __restrict__ out) {
  int idx = blockIdx.x * 256 + threadIdx.x;
  if (idx >= 192 * NPX) return;
  int m = idx / NPX, n = idx % NPX;
  float s = b33[m];
#pragma unroll
  for (int c = 0; c < 9; c++) s += Cp2[(size_t)c * 192 * NPX + idx];
  int bb = n / OHW, o = n % OHW;
  int cc = 384 + m;
  float scale = rsqrtf(bn_v[cc] + EPSF) * bn_g[cc];
  float v = s * scale + (bn_b[cc] - bn_m[cc] * scale);
  float a = prelu_a[0];
  out[((size_t)bb * 576 + cc) * OHW + o] = v > 0.f ? v : a * v;
}

extern "C" void kernel_launch(void* const* d_in, const int* in_sizes, int n_in,
                              void* d_out, int out_size, void* d_ws, size_t ws_size,
                              hipStream_t stream) {
  const float* x        = (const float*)d_in[0];
  const float* ln_g     = (const float*)d_in[1];
  const float* ln_b     = (const float*)d_in[2];
  const float* in_proj_w= (const float*)d_in[3];
  const float* dwconv_w = (const float*)d_in[4];
  const float* dwconv_b = (const float*)d_in[5];
  const float* x_proj_w = (const float*)d_in[6];
  const float* dt_w     = (const float*)d_in[7];
  const float* dt_b     = (const float*)d_in[8];
  const float* A_logs   = (const float*)d_in[9];
  const float* Ds       = (const float*)d_in[10];
  const float* out_norm_g = (const float*)d_in[11];
  const float* out_norm_b = (const float*)d_in[12];
  const float* out_proj_w = (const float*)d_in[13];
  const float* w1  = (const float*)d_in[14];
  const float* b1  = (const float*)d_in[15];
  const float* w31 = (const float*)d_in[16];
  const float* b31 = (const float*)d_in[17];
  const float* w32 = (const float*)d_in[18];
  const float* b32 = (const float*)d_in[19];
  const float* w33 = (const float*)d_in[20];
  const float* b33 = (const float*)d_in[21];
  const float* bn_g = (const float*)d_in[22];
  const float* bn_b = (const float*)d_in[23];
  const float* bn_m = (const float*)d_in[24];
  const float* bn_v = (const float*)d_in[25];
  const float* prelu_a = (const float*)d_in[26];

  float* ws = (float*)d_ws;
  float* stats = ws + 0;           //   9216
  float* WgT   = ws + 16384;       //  36864
  float* sWg   = ws + 65536;       //    384
  float* sWb   = ws + 66048;       //    384
  float* At3   = ws + 98304;       //  36864
  short* At1b  = (short*)(ws + 147456);   // 497664 shorts
  short* At2b  = (short*)(ws + 397312);   // 331776 shorts
  short* woutb = (short*)(ws + 565248);   //  18432 shorts
  float* xin   = ws + 2097152;     // 884736
  float* z     = ws + 3145728;     // 884736
  float* xs    = ws + 4194304;     // 1769472
  float* xsl   = ws + 8388608;     // 884736
  float* C1    = ws + 9437184;     // 884736
  float* delta = ws + 10485760;    // 3538944
  float* Bsb   = ws + 14155776;    // 294912
  float* Csb   = ws + 14680064;    // 294912
  float* Pbuf  = ws + 15728640;    // 2359296
  float* Sbuf  = ws + 18874368;    // 2359296
  float* Hinit = ws + 22020096;    // 2359296
  float* ys    = ws + 25165824;    // 3538944
  float* xm    = ws + 29360128;    // 442368
  float* t3    = ws + 30408704;    // 221184
  float* Cp1   = ws + 31457280;    // 5971968 (9 x 576 x 1152)
  float* Cp2   = ws + 37748736;    // 1990656 (9 x 192 x 1152)
  float* out = (float*)d_out;

  k_prep<<<3529, 256, 0, stream>>>(x, ln_g, ln_b, in_proj_w, x_proj_w,
                                   w31, w32, w33, w1, out_proj_w,
                                   stats, WgT, sWg, sWb, At3, At1b, At2b, woutb);
  k_gemmF<384, 96><<<dim3(36, 6, 2), 256, 0, stream>>>(
      WgT, x, LL, CIN * LL, xin, LL, DD * LL, stats, sWg, sWb, z);
  k_dwconv<<<576, 256, 0, stream>>>(xin, dwconv_w, dwconv_b, xs, xsl);
  k_gemm<192, 192, NTOT><<<dim3(72, 3, 1), 256, 0, stream>>>(At3, xsl, C1);
  k_dtsplit<<<576, 256, 0, stream>>>(C1, dt_w, dt_b, Bsb, Csb, delta);
  k_scan1<<<768, 192, 0, stream>>>(delta, xs, Bsb, A_logs, Pbuf, Sbuf);
  k_scan2<<<96, 256, 0, stream>>>(Pbuf, Sbuf, Hinit);
  k_scan3<<<768, 192, 0, stream>>>(delta, xs, Bsb, Csb, A_logs, Ds, Hinit, ys);
  k_combineF<<<144, 256, 0, stream>>>(ys, z, out_norm_g, out_norm_b, woutb, x, xm);
  // conv1+2 (+1x1): M=576, K=864, split-K 9, bf16 MFMA
  k_cgemm_mfma<576, 864, 96, CIN, HH, 2><<<dim3(18, 9, 9), 256, 0, stream>>>(
      At1b, xm, Cp1);
  k_reduce1<<<2592, 256, 0, stream>>>(Cp1, b1, b31, b32, bn_g, bn_b, bn_m, bn_v,
                                      prelu_a, out, t3);
  // conv3b: M=192, K=1728, split-K 9, bf16 MFMA
  k_cgemm_mfma<192, 1728, 192, COUT, OH, 1><<<dim3(18, 3, 9), 256, 0, stream>>>(
      At2b, t3, Cp2);
  k_reduce2<<<864, 256, 0, stream>>>(Cp2, b33, bn_g, bn_b, bn_m, bn_v, prelu_a, out);
}